// Round 1
// baseline (15488.663 us; speedup 1.0000x reference)
//
#include <hip/hip_runtime.h>

#define Nn 50000
#define Ee 800000
#define Tt 12
// HID = 128, K = 3, F_IN = 7 (x_prev + 4 env + 2 coords), CIN = 135

__device__ __forceinline__ void atomAdd(float* p, float v) {
    unsafeAtomicAdd(p, v);
}

// ---- degree accumulation --------------------------------------------------
__global__ __launch_bounds__(256) void deg_kernel(
    const int* __restrict__ ei, const float* __restrict__ ew,
    float* __restrict__ deg_out, float* __restrict__ deg_in)
{
    int e = blockIdx.x * blockDim.x + threadIdx.x;
    if (e >= Ee) return;
    int r = ei[e];
    int c = ei[Ee + e];
    float w = ew[e];
    atomAdd(&deg_out[r], w);
    atomAdd(&deg_in[c], w);
}

// ---- effective weights: 35x128 per gate, stored transposed [j*36 + k] -----
// f layout: [0..6]=X, [7..13]=Tx_o, [14..20]=Tx_i, [21..27]=Tx_o2, [28..34]=Tx_i2
__global__ __launch_bounds__(256) void weff_kernel(
    const float* __restrict__ Wz, const float* __restrict__ Wh,
    float* __restrict__ wzT, float* __restrict__ whT)
{
    int idx = blockIdx.x * blockDim.x + threadIdx.x;
    if (idx >= 2 * 128 * 36) return;
    const float* W = (idx < 128 * 36) ? Wz : Wh;
    float* O       = (idx < 128 * 36) ? wzT : whT;
    int rem = idx % (128 * 36);
    int j = rem / 36;
    int k = rem % 36;
    float v = 0.f;
    if (k < 35) {
        int p = k / 7, rr = k % 7;
        // W flat index: ((d*3 + kk)*135 + rr)*128 + j
        if (p == 0)      v = W[((0*3+0)*135+rr)*128+j] + W[((1*3+0)*135+rr)*128+j];
        else if (p == 1) v = W[((0*3+1)*135+rr)*128+j];
        else if (p == 2) v = W[((1*3+1)*135+rr)*128+j];
        else if (p == 3) v = W[((0*3+2)*135+rr)*128+j];
        else             v = W[((1*3+2)*135+rr)*128+j];
    }
    O[j*36 + k] = v;
}

// ---- per-node init: inverse degrees, X0, zero S buffers, out column 0 -----
__global__ __launch_bounds__(256) void init_kernel(
    const float* __restrict__ x, const float* __restrict__ env,
    const float* __restrict__ coords,
    const float* __restrict__ deg_out, const float* __restrict__ deg_in,
    float* __restrict__ inv_out, float* __restrict__ inv_in,
    float* __restrict__ X,
    float* __restrict__ S1o, float* __restrict__ S1i,
    float* __restrict__ S2o, float* __restrict__ S2i,
    float* __restrict__ out)
{
    int i = blockIdx.x * blockDim.x + threadIdx.x;
    if (i >= Nn) return;
    float dout = deg_out[i], din = deg_in[i];
    inv_out[i] = dout > 0.f ? 1.f / dout : 0.f;
    inv_in[i]  = din  > 0.f ? 1.f / din  : 0.f;
    float xv = x[i * Tt];      // x[:, 0]
    X[i*8 + 0] = xv;
    #pragma unroll
    for (int c = 0; c < 4; c++) X[i*8 + 1 + c] = env[i*48 + c*12 + 0];
    X[i*8 + 5] = coords[i*2 + 0];
    X[i*8 + 6] = coords[i*2 + 1];
    X[i*8 + 7] = 0.f;
    float4 z4 = make_float4(0.f, 0.f, 0.f, 0.f);
    float4* p;
    p = (float4*)(S1o + i*8); p[0] = z4; p[1] = z4;
    p = (float4*)(S1i + i*8); p[0] = z4; p[1] = z4;
    p = (float4*)(S2o + i*8); p[0] = z4; p[1] = z4;
    p = (float4*)(S2i + i*8); p[0] = z4; p[1] = z4;
    out[i*13 + 0] = xv;        // predictions[:, 0] = x0
}

// ---- first-order propagation: raw weighted segment sums -------------------
__global__ __launch_bounds__(256) void edge_pass1(
    const int* __restrict__ ei, const float* __restrict__ ew,
    const float* __restrict__ X,
    float* __restrict__ S1o, float* __restrict__ S1i)
{
    int e = blockIdx.x * blockDim.x + threadIdx.x;
    if (e >= Ee) return;
    int r = ei[e];
    int c = ei[Ee + e];
    float w = ew[e];
    const float4* Xv = (const float4*)X;
    float4 c0 = Xv[c*2], c1 = Xv[c*2 + 1];   // X[col] -> scatter to row (prop_out)
    float4 r0 = Xv[r*2], r1 = Xv[r*2 + 1];   // X[row] -> scatter to col (prop_in)
    float* po = S1o + r*8;
    float* pi = S1i + c*8;
    atomAdd(po+0, w*c0.x); atomAdd(po+1, w*c0.y); atomAdd(po+2, w*c0.z);
    atomAdd(po+3, w*c0.w); atomAdd(po+4, w*c1.x); atomAdd(po+5, w*c1.y);
    atomAdd(po+6, w*c1.z);
    atomAdd(pi+0, w*r0.x); atomAdd(pi+1, w*r0.y); atomAdd(pi+2, w*r0.z);
    atomAdd(pi+3, w*r0.w); atomAdd(pi+4, w*r1.x); atomAdd(pi+5, w*r1.y);
    atomAdd(pi+6, w*r1.z);
}

// ---- second-order propagation: gather normalized Tx, scatter raw sums -----
__global__ __launch_bounds__(256) void edge_pass2(
    const int* __restrict__ ei, const float* __restrict__ ew,
    const float* __restrict__ inv_out, const float* __restrict__ inv_in,
    const float* __restrict__ S1o, const float* __restrict__ S1i,
    float* __restrict__ S2o, float* __restrict__ S2i)
{
    int e = blockIdx.x * blockDim.x + threadIdx.x;
    if (e >= Ee) return;
    int r = ei[e];
    int c = ei[Ee + e];
    float w = ew[e];
    float so = w * inv_out[c];   // Tx_o[c] = inv_out[c] * S1o[c]
    float si = w * inv_in[r];    // Tx_i[r] = inv_in[r]  * S1i[r]
    const float4* Ao = (const float4*)S1o;
    const float4* Ai = (const float4*)S1i;
    float4 c0 = Ao[c*2], c1 = Ao[c*2 + 1];
    float4 r0 = Ai[r*2], r1 = Ai[r*2 + 1];
    float* po = S2o + r*8;
    float* pi = S2i + c*8;
    atomAdd(po+0, so*c0.x); atomAdd(po+1, so*c0.y); atomAdd(po+2, so*c0.z);
    atomAdd(po+3, so*c0.w); atomAdd(po+4, so*c1.x); atomAdd(po+5, so*c1.y);
    atomAdd(po+6, so*c1.z);
    atomAdd(pi+0, si*r0.x); atomAdd(pi+1, si*r0.y); atomAdd(pi+2, si*r0.z);
    atomAdd(pi+3, si*r0.w); atomAdd(pi+4, si*r1.x); atomAdd(pi+5, si*r1.y);
    atomAdd(pi+6, si*r1.z);
}

// ---- fused node step: build f(35), 2x (35x128) contraction, activations, --
// ---- lin output, night scale, S-zero for next step, next X ----------------
__global__ __launch_bounds__(256) void node_step_kernel(
    const float* __restrict__ env, const float* __restrict__ night,
    const float* __restrict__ wzT, const float* __restrict__ whT,
    const float* __restrict__ bz, const float* __restrict__ bh,
    const float* __restrict__ linW, const float* __restrict__ linb,
    float* __restrict__ X,
    float* __restrict__ S1o, float* __restrict__ S1i,
    float* __restrict__ S2o, float* __restrict__ S2i,
    const float* __restrict__ inv_out, const float* __restrict__ inv_in,
    float* __restrict__ out, int t)
{
    int i = blockIdx.x * blockDim.x + threadIdx.x;
    if (i >= Nn) return;
    float io = inv_out[i], ii = inv_in[i];
    float f[35];
    #pragma unroll
    for (int k = 0; k < 7; k++) f[k]      = X[i*8 + k];
    #pragma unroll
    for (int k = 0; k < 7; k++) f[7 + k]  = io * S1o[i*8 + k];
    #pragma unroll
    for (int k = 0; k < 7; k++) f[14 + k] = ii * S1i[i*8 + k];
    #pragma unroll
    for (int k = 0; k < 7; k++) f[21 + k] = 2.f * io * S2o[i*8 + k] - f[k];
    #pragma unroll
    for (int k = 0; k < 7; k++) f[28 + k] = 2.f * ii * S2i[i*8 + k] - f[k];

    float acc = 0.f;
    #pragma unroll 2
    for (int j = 0; j < 128; j++) {
        float hz = bz[j];
        float hh = bh[j];
        #pragma unroll
        for (int k = 0; k < 35; k++) {
            hz = fmaf(f[k], wzT[j*36 + k], hz);
            hh = fmaf(f[k], whT[j*36 + k], hh);
        }
        float z  = 1.f / (1.f + __expf(-hz));        // sigmoid
        float e2 = __expf(2.f * hh);
        float ht = 1.f - 2.f / (e2 + 1.f);           // tanh
        float hn = (1.f - z) * ht;                   // Z*0 + (1-Z)*H~
        acc = fmaf(fmaxf(hn, 0.f), linW[j], acc);    // relu @ lin_W
    }
    float o = acc + linb[0];
    o *= night[i*13 + t + 1];
    out[i*13 + t + 1] = o;

    // zero S buffers for next step
    float4 z4 = make_float4(0.f, 0.f, 0.f, 0.f);
    float4* p;
    p = (float4*)(S1o + i*8); p[0] = z4; p[1] = z4;
    p = (float4*)(S1i + i*8); p[0] = z4; p[1] = z4;
    p = (float4*)(S2o + i*8); p[0] = z4; p[1] = z4;
    p = (float4*)(S2i + i*8); p[0] = z4; p[1] = z4;

    // build next X (x_prev = this step's out, env advances; coords unchanged)
    if (t + 1 < Tt) {
        X[i*8 + 0] = o;
        #pragma unroll
        for (int c = 0; c < 4; c++) X[i*8 + 1 + c] = env[i*48 + c*12 + (t + 1)];
    }
}

extern "C" void kernel_launch(void* const* d_in, const int* in_sizes, int n_in,
                              void* d_out, int out_size, void* d_ws, size_t ws_size,
                              hipStream_t stream) {
    const float* x      = (const float*)d_in[0];
    const float* env    = (const float*)d_in[1];
    const float* coords = (const float*)d_in[2];
    const int*   ei     = (const int*)d_in[3];
    const float* ew     = (const float*)d_in[4];
    const float* night  = (const float*)d_in[5];
    const float* Wz     = (const float*)d_in[6];
    const float* bz     = (const float*)d_in[7];
    // d_in[8] = Wr, d_in[9] = br  -> unused (R gate never affects output)
    const float* Wh     = (const float*)d_in[10];
    const float* bh     = (const float*)d_in[11];
    const float* linW   = (const float*)d_in[12];
    const float* linb   = (const float*)d_in[13];
    float* out = (float*)d_out;

    float* w = (float*)d_ws;
    float* deg_out = w;
    float* deg_in  = w + Nn;
    float* inv_out = w + 2*Nn;
    float* inv_in  = w + 3*Nn;
    float* X   = w + 4*Nn;    // N x 8 (7 features + pad)
    float* S1o = w + 12*Nn;   // N x 8
    float* S1i = w + 20*Nn;
    float* S2o = w + 28*Nn;
    float* S2i = w + 36*Nn;
    float* wzT = w + 44*Nn;   // 128 x 36 (transposed effective weights)
    float* whT = wzT + 128*36;

    hipMemsetAsync(deg_out, 0, 2 * Nn * sizeof(float), stream);
    deg_kernel<<<(Ee + 255) / 256, 256, 0, stream>>>(ei, ew, deg_out, deg_in);
    weff_kernel<<<(2*128*36 + 255) / 256, 256, 0, stream>>>(Wz, Wh, wzT, whT);
    init_kernel<<<(Nn + 255) / 256, 256, 0, stream>>>(
        x, env, coords, deg_out, deg_in, inv_out, inv_in,
        X, S1o, S1i, S2o, S2i, out);

    for (int t = 0; t < Tt; t++) {
        edge_pass1<<<(Ee + 255) / 256, 256, 0, stream>>>(ei, ew, X, S1o, S1i);
        edge_pass2<<<(Ee + 255) / 256, 256, 0, stream>>>(
            ei, ew, inv_out, inv_in, S1o, S1i, S2o, S2i);
        node_step_kernel<<<(Nn + 255) / 256, 256, 0, stream>>>(
            env, night, wzT, whT, bz, bh, linW, linb,
            X, S1o, S1i, S2o, S2i, inv_out, inv_in, out, t);
    }
}

// Round 2
// 1258.636 us; speedup vs baseline: 12.3059x; 12.3059x over previous
//
#include <hip/hip_runtime.h>

#define Nn 50000
#define Ee 800000
#define Tt 12
// HID=128, K=3, F_IN=7, effective features = 35 (+1 bias slot)

// =================== CSR build (once per launch) ===========================
__global__ __launch_bounds__(256) void hist_kernel(
    const int* __restrict__ ei, int* __restrict__ cntR, int* __restrict__ cntC)
{
    int e = blockIdx.x * 256 + threadIdx.x;
    if (e >= Ee) return;
    atomicAdd(&cntR[ei[e]], 1);
    atomicAdd(&cntC[ei[Ee + e]], 1);
}

__global__ __launch_bounds__(1024) void scan_kernel(
    const int* __restrict__ cnt, int* __restrict__ rowptr, int* __restrict__ nextp)
{
    __shared__ int part[1024];
    int t = threadIdx.x;
    const int chunk = (Nn + 1023) / 1024;   // 49
    int lo = t * chunk;
    int hi = min(lo + chunk, Nn);
    int s = 0;
    for (int i = lo; i < hi; i++) s += cnt[i];
    part[t] = s;
    __syncthreads();
    for (int off = 1; off < 1024; off <<= 1) {
        int v = (t >= off) ? part[t - off] : 0;
        __syncthreads();
        part[t] += v;
        __syncthreads();
    }
    int base = (t == 0) ? 0 : part[t - 1];
    for (int i = lo; i < hi; i++) { rowptr[i] = base; nextp[i] = base; base += cnt[i]; }
    if (t == 1023) rowptr[Nn] = part[1023];
}

__global__ __launch_bounds__(256) void scatter_kernel(
    const int* __restrict__ ei, const float* __restrict__ ew,
    int* __restrict__ nextR, int* __restrict__ nextC,
    int2* __restrict__ adjR, int2* __restrict__ adjC)
{
    int e = blockIdx.x * 256 + threadIdx.x;
    if (e >= Ee) return;
    int r = ei[e], c = ei[Ee + e];
    int wb = __float_as_int(ew[e]);
    int pr = atomicAdd(&nextR[r], 1);
    adjR[pr] = make_int2(c, wb);      // row-sorted: (src=col, w) -> prop_out
    int pc = atomicAdd(&nextC[c], 1);
    adjC[pc] = make_int2(r, wb);      // col-sorted: (src=row, w) -> prop_in
}

// ============ effective weights 36x128 per gate, transposed, bias at k=35 ==
// f layout: [0..6]=X, [7..13]=Tx_o, [14..20]=Tx_i, [21..27]=Tx_o2, [28..34]=Tx_i2, [35]=1
__global__ __launch_bounds__(256) void weff_kernel(
    const float* __restrict__ Wz, const float* __restrict__ Wh,
    const float* __restrict__ bz, const float* __restrict__ bh,
    float* __restrict__ wzT, float* __restrict__ whT)
{
    int idx = blockIdx.x * 256 + threadIdx.x;
    if (idx >= 2 * 128 * 36) return;
    const float* W = (idx < 128 * 36) ? Wz : Wh;
    const float* B = (idx < 128 * 36) ? bz : bh;
    float* O       = (idx < 128 * 36) ? wzT : whT;
    int rem = idx % (128 * 36);
    int j = rem / 36, k = rem % 36;
    float v;
    if (k == 35) v = B[j];
    else {
        int p = k / 7, rr = k % 7;
        // W flat: ((d*3 + kk)*135 + rr)*128 + j
        if (p == 0)      v = W[(0 * 135 + rr) * 128 + j] + W[(3 * 135 + rr) * 128 + j];
        else if (p == 1) v = W[(1 * 135 + rr) * 128 + j];
        else if (p == 2) v = W[(4 * 135 + rr) * 128 + j];
        else if (p == 3) v = W[(2 * 135 + rr) * 128 + j];
        else             v = W[(5 * 135 + rr) * 128 + j];
    }
    O[j * 36 + k] = v;
}

// =================== init: X0 and out column 0 =============================
__global__ __launch_bounds__(256) void init_kernel(
    const float* __restrict__ x, const float* __restrict__ env,
    const float* __restrict__ coords, float* __restrict__ X, float* __restrict__ out)
{
    int i = blockIdx.x * 256 + threadIdx.x;
    if (i >= Nn) return;
    float xv = x[i * Tt];
    X[i * 8 + 0] = xv;
    #pragma unroll
    for (int c = 0; c < 4; c++) X[i * 8 + 1 + c] = env[i * 48 + c * 12];
    X[i * 8 + 5] = coords[i * 2 + 0];
    X[i * 8 + 6] = coords[i * 2 + 1];
    X[i * 8 + 7] = 0.f;
    out[i * 13 + 0] = xv;
}

// ============== gather pass 1: Txo/Txi = inv * segsum(w * X[src]) ==========
// 8 threads per node: dir = out/in, 4 sub-threads per direction.
__global__ __launch_bounds__(256) void gather1_kernel(
    const int* __restrict__ rowptrR, const int2* __restrict__ adjR,
    const int* __restrict__ rowptrC, const int2* __restrict__ adjC,
    const float* __restrict__ X,
    float* __restrict__ Txo, float* __restrict__ Txi,
    float* __restrict__ inv_out, float* __restrict__ inv_in)
{
    int tid = blockIdx.x * 256 + threadIdx.x;
    if (tid >= Nn * 8) return;
    int node = tid >> 3;
    int s3 = tid & 7;
    int dir = s3 >> 2, sub = s3 & 3;
    const int*  rp  = dir ? rowptrC : rowptrR;
    const int2* adj = dir ? adjC : adjR;
    int b = rp[node], e = rp[node + 1];
    float4 a0 = make_float4(0.f, 0.f, 0.f, 0.f);
    float4 a1 = make_float4(0.f, 0.f, 0.f, 0.f);
    float sw = 0.f;
    for (int k = b + sub; k < e; k += 4) {
        int2 ed = adj[k];
        float w = __int_as_float(ed.y);
        const float4* Xv = (const float4*)(X + (long)ed.x * 8);
        float4 x0 = Xv[0], x1 = Xv[1];
        a0.x = fmaf(w, x0.x, a0.x); a0.y = fmaf(w, x0.y, a0.y);
        a0.z = fmaf(w, x0.z, a0.z); a0.w = fmaf(w, x0.w, a0.w);
        a1.x = fmaf(w, x1.x, a1.x); a1.y = fmaf(w, x1.y, a1.y);
        a1.z = fmaf(w, x1.z, a1.z);
        sw += w;
    }
    #pragma unroll
    for (int m = 1; m <= 2; m <<= 1) {
        a0.x += __shfl_xor(a0.x, m); a0.y += __shfl_xor(a0.y, m);
        a0.z += __shfl_xor(a0.z, m); a0.w += __shfl_xor(a0.w, m);
        a1.x += __shfl_xor(a1.x, m); a1.y += __shfl_xor(a1.y, m);
        a1.z += __shfl_xor(a1.z, m);
        sw   += __shfl_xor(sw,   m);
    }
    if (sub == 0) {
        float inv = sw > 0.f ? 1.f / sw : 0.f;
        float* T = dir ? Txi : Txo;
        float* I = dir ? inv_in : inv_out;
        I[node] = inv;
        float4* Tv = (float4*)(T + (long)node * 8);
        Tv[0] = make_float4(a0.x * inv, a0.y * inv, a0.z * inv, a0.w * inv);
        Tv[1] = make_float4(a1.x * inv, a1.y * inv, a1.z * inv, 0.f);
    }
}

// ======= gather pass 2: T2 = 2*inv*segsum(w * Tx[src]) - X[node] ===========
__global__ __launch_bounds__(256) void gather2_kernel(
    const int* __restrict__ rowptrR, const int2* __restrict__ adjR,
    const int* __restrict__ rowptrC, const int2* __restrict__ adjC,
    const float* __restrict__ X,
    const float* __restrict__ Txo, const float* __restrict__ Txi,
    const float* __restrict__ inv_out, const float* __restrict__ inv_in,
    float* __restrict__ T2o, float* __restrict__ T2i)
{
    int tid = blockIdx.x * 256 + threadIdx.x;
    if (tid >= Nn * 8) return;
    int node = tid >> 3;
    int s3 = tid & 7;
    int dir = s3 >> 2, sub = s3 & 3;
    const int*   rp  = dir ? rowptrC : rowptrR;
    const int2*  adj = dir ? adjC : adjR;
    const float* src = dir ? Txi : Txo;
    int b = rp[node], e = rp[node + 1];
    float4 a0 = make_float4(0.f, 0.f, 0.f, 0.f);
    float4 a1 = make_float4(0.f, 0.f, 0.f, 0.f);
    for (int k = b + sub; k < e; k += 4) {
        int2 ed = adj[k];
        float w = __int_as_float(ed.y);
        const float4* Sv = (const float4*)(src + (long)ed.x * 8);
        float4 x0 = Sv[0], x1 = Sv[1];
        a0.x = fmaf(w, x0.x, a0.x); a0.y = fmaf(w, x0.y, a0.y);
        a0.z = fmaf(w, x0.z, a0.z); a0.w = fmaf(w, x0.w, a0.w);
        a1.x = fmaf(w, x1.x, a1.x); a1.y = fmaf(w, x1.y, a1.y);
        a1.z = fmaf(w, x1.z, a1.z);
    }
    #pragma unroll
    for (int m = 1; m <= 2; m <<= 1) {
        a0.x += __shfl_xor(a0.x, m); a0.y += __shfl_xor(a0.y, m);
        a0.z += __shfl_xor(a0.z, m); a0.w += __shfl_xor(a0.w, m);
        a1.x += __shfl_xor(a1.x, m); a1.y += __shfl_xor(a1.y, m);
        a1.z += __shfl_xor(a1.z, m);
    }
    if (sub == 0) {
        float s2 = 2.f * (dir ? inv_in[node] : inv_out[node]);
        const float4* Xv = (const float4*)(X + (long)node * 8);
        float4 x0 = Xv[0], x1 = Xv[1];
        float* T = dir ? T2i : T2o;
        float4* Tv = (float4*)(T + (long)node * 8);
        Tv[0] = make_float4(fmaf(s2, a0.x, -x0.x), fmaf(s2, a0.y, -x0.y),
                            fmaf(s2, a0.z, -x0.z), fmaf(s2, a0.w, -x0.w));
        Tv[1] = make_float4(fmaf(s2, a1.x, -x1.x), fmaf(s2, a1.y, -x1.y),
                            fmaf(s2, a1.z, -x1.z), 0.f);
    }
}

// ====== node step: dense 36x128x2 contraction + activations + output =======
// 4 threads per node, each handles 32 channels; weights staged in LDS.
__global__ __launch_bounds__(256) void node_step_kernel(
    const float* __restrict__ env, const float* __restrict__ night,
    const float* __restrict__ wzT, const float* __restrict__ whT,
    const float* __restrict__ linW, const float* __restrict__ linb,
    float* __restrict__ X,
    const float* __restrict__ Txo, const float* __restrict__ Txi,
    const float* __restrict__ T2o, const float* __restrict__ T2i,
    float* __restrict__ out, int t)
{
    __shared__ float wz_s[128 * 36];
    __shared__ float wh_s[128 * 36];
    __shared__ float lw_s[128];
    for (int idx = threadIdx.x; idx < 128 * 36; idx += 256) {
        wz_s[idx] = wzT[idx];
        wh_s[idx] = whT[idx];
    }
    if (threadIdx.x < 128) lw_s[threadIdx.x] = linW[threadIdx.x];
    __syncthreads();

    int tid = blockIdx.x * 256 + threadIdx.x;
    if (tid >= Nn * 4) return;
    int node = tid >> 2;
    int sub = tid & 3;

    float f[36];
    {
        const float* p;
        p = X   + (long)node * 8;
        #pragma unroll
        for (int k = 0; k < 7; k++) f[k] = p[k];
        p = Txo + (long)node * 8;
        #pragma unroll
        for (int k = 0; k < 7; k++) f[7 + k] = p[k];
        p = Txi + (long)node * 8;
        #pragma unroll
        for (int k = 0; k < 7; k++) f[14 + k] = p[k];
        p = T2o + (long)node * 8;
        #pragma unroll
        for (int k = 0; k < 7; k++) f[21 + k] = p[k];
        p = T2i + (long)node * 8;
        #pragma unroll
        for (int k = 0; k < 7; k++) f[28 + k] = p[k];
        f[35] = 1.f;
    }

    float acc = 0.f;
    #pragma unroll 4
    for (int jj = 0; jj < 32; jj++) {
        int j = jj * 4 + sub;   // 36*sub apart -> distinct banks, broadcast across nodes
        const float* wz = wz_s + j * 36;
        const float* wh = wh_s + j * 36;
        float hz = 0.f, hh = 0.f;
        #pragma unroll
        for (int k = 0; k < 36; k++) {
            hz = fmaf(f[k], wz[k], hz);
            hh = fmaf(f[k], wh[k], hh);
        }
        float z  = 1.f / (1.f + __expf(-hz));
        float e2 = __expf(2.f * hh);
        float ht = 1.f - 2.f / (e2 + 1.f);       // tanh
        float hn = (1.f - z) * ht;               // (1-Z)*H~  (hid0 == 0)
        acc = fmaf(fmaxf(hn, 0.f), lw_s[j], acc);
    }
    acc += __shfl_xor(acc, 1);
    acc += __shfl_xor(acc, 2);

    if (sub == 0) {
        float o = acc + linb[0];
        o *= night[(long)node * 13 + t + 1];
        out[(long)node * 13 + t + 1] = o;
        if (t + 1 < Tt) {
            X[(long)node * 8 + 0] = o;
            #pragma unroll
            for (int c = 0; c < 4; c++)
                X[(long)node * 8 + 1 + c] = env[(long)node * 48 + c * 12 + (t + 1)];
        }
    }
}

extern "C" void kernel_launch(void* const* d_in, const int* in_sizes, int n_in,
                              void* d_out, int out_size, void* d_ws, size_t ws_size,
                              hipStream_t stream) {
    const float* x      = (const float*)d_in[0];
    const float* env    = (const float*)d_in[1];
    const float* coords = (const float*)d_in[2];
    const int*   ei     = (const int*)d_in[3];
    const float* ew     = (const float*)d_in[4];
    const float* night  = (const float*)d_in[5];
    const float* Wz     = (const float*)d_in[6];
    const float* bz     = (const float*)d_in[7];
    // d_in[8]=Wr, d_in[9]=br unused (R gate never affects output)
    const float* Wh     = (const float*)d_in[10];
    const float* bh     = (const float*)d_in[11];
    const float* linW   = (const float*)d_in[12];
    const float* linb   = (const float*)d_in[13];
    float* out = (float*)d_out;

    float* w = (float*)d_ws;
    float* X       = w;                   // N x 8
    float* Txo     = w + 400000;          // N x 8
    float* Txi     = w + 800000;
    float* T2o     = w + 1200000;
    float* T2i     = w + 1600000;
    float* inv_out = w + 2000000;         // N
    float* inv_in  = w + 2050000;
    float* wzT     = w + 2100000;         // 128*36
    float* whT     = w + 2104608;
    int* cntR      = (int*)(w + 2109216); // N
    int* cntC      = cntR + 50000;
    int* rowptrR   = cntC + 50000;        // N+1
    int* rowptrC   = rowptrR + 50001;
    int* nextR     = rowptrC + 50001;     // N
    int* nextC     = nextR + 50000;
    int2* adjR     = (int2*)(nextC + 50000);  // E   (word offset even -> 8B aligned)
    int2* adjC     = adjR + Ee;

    // ---- CSR build (per launch; ws is re-poisoned every call) ----
    hipMemsetAsync(cntR, 0, 2 * Nn * sizeof(int), stream);
    hist_kernel<<<(Ee + 255) / 256, 256, 0, stream>>>(ei, cntR, cntC);
    scan_kernel<<<1, 1024, 0, stream>>>(cntR, rowptrR, nextR);
    scan_kernel<<<1, 1024, 0, stream>>>(cntC, rowptrC, nextC);
    scatter_kernel<<<(Ee + 255) / 256, 256, 0, stream>>>(ei, ew, nextR, nextC, adjR, adjC);

    weff_kernel<<<(2 * 128 * 36 + 255) / 256, 256, 0, stream>>>(Wz, Wh, bz, bh, wzT, whT);
    init_kernel<<<(Nn + 255) / 256, 256, 0, stream>>>(x, env, coords, X, out);

    for (int t = 0; t < Tt; t++) {
        gather1_kernel<<<(Nn * 8 + 255) / 256, 256, 0, stream>>>(
            rowptrR, adjR, rowptrC, adjC, X, Txo, Txi, inv_out, inv_in);
        gather2_kernel<<<(Nn * 8 + 255) / 256, 256, 0, stream>>>(
            rowptrR, adjR, rowptrC, adjC, X, Txo, Txi, inv_out, inv_in, T2o, T2i);
        node_step_kernel<<<(Nn * 4 + 255) / 256, 256, 0, stream>>>(
            env, night, wzT, whT, linW, linb, X, Txo, Txi, T2o, T2i, out, t);
    }
}

// Round 3
// 1216.937 us; speedup vs baseline: 12.7276x; 1.0343x over previous
//
#include <hip/hip_runtime.h>
#include <hip/hip_fp16.h>

#define Nn 50000
#define Ee 800000
#define Tt 12
// HID=128, K=3, F_IN=7, effective features = 35 (+1 bias slot)
// Adjacency entry: (src_node << 16) | half_bits(edge_weight)  -- 4 bytes.

// =================== CSR build (once per launch) ===========================
__global__ __launch_bounds__(256) void hist_kernel(
    const int* __restrict__ ei, int* __restrict__ cntR, int* __restrict__ cntC)
{
    int e = blockIdx.x * 256 + threadIdx.x;
    if (e >= Ee) return;
    atomicAdd(&cntR[ei[e]], 1);
    atomicAdd(&cntC[ei[Ee + e]], 1);
}

__global__ __launch_bounds__(1024) void scan_kernel(
    const int* __restrict__ cnt, int* __restrict__ rowptr, int* __restrict__ nextp)
{
    __shared__ int part[1024];
    int t = threadIdx.x;
    const int chunk = (Nn + 1023) / 1024;   // 49
    int lo = t * chunk;
    int hi = min(lo + chunk, Nn);
    int s = 0;
    for (int i = lo; i < hi; i++) s += cnt[i];
    part[t] = s;
    __syncthreads();
    for (int off = 1; off < 1024; off <<= 1) {
        int v = (t >= off) ? part[t - off] : 0;
        __syncthreads();
        part[t] += v;
        __syncthreads();
    }
    int base = (t == 0) ? 0 : part[t - 1];
    for (int i = lo; i < hi; i++) { rowptr[i] = base; nextp[i] = base; base += cnt[i]; }
    if (t == 1023) rowptr[Nn] = part[1023];
}

__global__ __launch_bounds__(256) void scatter_kernel(
    const int* __restrict__ ei, const float* __restrict__ ew,
    int* __restrict__ nextR, int* __restrict__ nextC,
    unsigned* __restrict__ adjR, unsigned* __restrict__ adjC)
{
    int e = blockIdx.x * 256 + threadIdx.x;
    if (e >= Ee) return;
    int r = ei[e], c = ei[Ee + e];
    unsigned wb = __half_as_ushort(__float2half(ew[e]));
    unsigned er = ((unsigned)c << 16) | wb;   // row-sorted list: src = col (prop_out)
    unsigned ec = ((unsigned)r << 16) | wb;   // col-sorted list: src = row (prop_in)
    adjR[atomicAdd(&nextR[r], 1)] = er;
    adjC[atomicAdd(&nextC[c], 1)] = ec;
}

// ============ effective weights 36x128 per gate, transposed, bias at k=35 ==
// f layout: [0..6]=X, [7..13]=Tx_o, [14..20]=Tx_i, [21..27]=Tx_o2, [28..34]=Tx_i2, [35]=1
__global__ __launch_bounds__(256) void weff_kernel(
    const float* __restrict__ Wz, const float* __restrict__ Wh,
    const float* __restrict__ bz, const float* __restrict__ bh,
    float* __restrict__ wzT, float* __restrict__ whT)
{
    int idx = blockIdx.x * 256 + threadIdx.x;
    if (idx >= 2 * 128 * 36) return;
    const float* W = (idx < 128 * 36) ? Wz : Wh;
    const float* B = (idx < 128 * 36) ? bz : bh;
    float* O       = (idx < 128 * 36) ? wzT : whT;
    int rem = idx % (128 * 36);
    int j = rem / 36, k = rem % 36;
    float v;
    if (k == 35) v = B[j];
    else {
        int p = k / 7, rr = k % 7;
        // W flat: ((d*3 + kk)*135 + rr)*128 + j
        if (p == 0)      v = W[(0 * 135 + rr) * 128 + j] + W[(3 * 135 + rr) * 128 + j];
        else if (p == 1) v = W[(1 * 135 + rr) * 128 + j];
        else if (p == 2) v = W[(4 * 135 + rr) * 128 + j];
        else if (p == 3) v = W[(2 * 135 + rr) * 128 + j];
        else             v = W[(5 * 135 + rr) * 128 + j];
    }
    O[j * 36 + k] = v;
}

// =================== init: X0 and out column 0 =============================
__global__ __launch_bounds__(256) void init_kernel(
    const float* __restrict__ x, const float* __restrict__ env,
    const float* __restrict__ coords, float* __restrict__ X, float* __restrict__ out)
{
    int i = blockIdx.x * 256 + threadIdx.x;
    if (i >= Nn) return;
    float xv = x[i * Tt];
    X[i * 8 + 0] = xv;
    #pragma unroll
    for (int c = 0; c < 4; c++) X[i * 8 + 1 + c] = env[i * 48 + c * 12];
    X[i * 8 + 5] = coords[i * 2 + 0];
    X[i * 8 + 6] = coords[i * 2 + 1];
    X[i * 8 + 7] = 0.f;
    out[i * 13 + 0] = xv;
}

// ============== gather pass 1: Txo/Txi = inv * segsum(w * X[src]) ==========
// 8 threads per node: bit2 = dir (out/in), bits0-1 = sub.
__global__ __launch_bounds__(256) void gather1_kernel(
    const int* __restrict__ rowptrR, const unsigned* __restrict__ adjR,
    const int* __restrict__ rowptrC, const unsigned* __restrict__ adjC,
    const float* __restrict__ X,
    float* __restrict__ Txo, float* __restrict__ Txi,
    float* __restrict__ inv_out, float* __restrict__ inv_in)
{
    int tid = blockIdx.x * 256 + threadIdx.x;
    if (tid >= Nn * 8) return;
    int node = tid >> 3;
    int dir = (tid >> 2) & 1, sub = tid & 3;
    const int*      rp  = dir ? rowptrC : rowptrR;
    const unsigned* adj = dir ? adjC : adjR;
    int b = rp[node], e = rp[node + 1];
    float4 a0 = make_float4(0.f, 0.f, 0.f, 0.f);
    float4 a1 = make_float4(0.f, 0.f, 0.f, 0.f);
    float sw = 0.f;
    for (int k = b + sub; k < e; k += 4) {
        unsigned ed = adj[k];
        float w = __half2float(__ushort_as_half((unsigned short)(ed & 0xffffu)));
        int src = (int)(ed >> 16);
        const float4* Xv = (const float4*)(X + (long)src * 8);
        float4 x0 = Xv[0], x1 = Xv[1];
        a0.x = fmaf(w, x0.x, a0.x); a0.y = fmaf(w, x0.y, a0.y);
        a0.z = fmaf(w, x0.z, a0.z); a0.w = fmaf(w, x0.w, a0.w);
        a1.x = fmaf(w, x1.x, a1.x); a1.y = fmaf(w, x1.y, a1.y);
        a1.z = fmaf(w, x1.z, a1.z);
        sw += w;
    }
    #pragma unroll
    for (int m = 1; m <= 2; m <<= 1) {
        a0.x += __shfl_xor(a0.x, m); a0.y += __shfl_xor(a0.y, m);
        a0.z += __shfl_xor(a0.z, m); a0.w += __shfl_xor(a0.w, m);
        a1.x += __shfl_xor(a1.x, m); a1.y += __shfl_xor(a1.y, m);
        a1.z += __shfl_xor(a1.z, m);
        sw   += __shfl_xor(sw,   m);
    }
    if (sub == 0) {
        float inv = sw > 0.f ? 1.f / sw : 0.f;
        float* T = dir ? Txi : Txo;
        float* I = dir ? inv_in : inv_out;
        I[node] = inv;
        float4* Tv = (float4*)(T + (long)node * 8);
        Tv[0] = make_float4(a0.x * inv, a0.y * inv, a0.z * inv, a0.w * inv);
        Tv[1] = make_float4(a1.x * inv, a1.y * inv, a1.z * inv, 0.f);
    }
}

// ======= gather pass 2: T2 = 2*inv*segsum(w * Tx[src]) - X[node] ===========
__global__ __launch_bounds__(256) void gather2_kernel(
    const int* __restrict__ rowptrR, const unsigned* __restrict__ adjR,
    const int* __restrict__ rowptrC, const unsigned* __restrict__ adjC,
    const float* __restrict__ X,
    const float* __restrict__ Txo, const float* __restrict__ Txi,
    const float* __restrict__ inv_out, const float* __restrict__ inv_in,
    float* __restrict__ T2o, float* __restrict__ T2i)
{
    int tid = blockIdx.x * 256 + threadIdx.x;
    if (tid >= Nn * 8) return;
    int node = tid >> 3;
    int dir = (tid >> 2) & 1, sub = tid & 3;
    const int*      rp  = dir ? rowptrC : rowptrR;
    const unsigned* adj = dir ? adjC : adjR;
    const float*    src = dir ? Txi : Txo;
    int b = rp[node], e = rp[node + 1];
    float4 a0 = make_float4(0.f, 0.f, 0.f, 0.f);
    float4 a1 = make_float4(0.f, 0.f, 0.f, 0.f);
    for (int k = b + sub; k < e; k += 4) {
        unsigned ed = adj[k];
        float w = __half2float(__ushort_as_half((unsigned short)(ed & 0xffffu)));
        int s = (int)(ed >> 16);
        const float4* Sv = (const float4*)(src + (long)s * 8);
        float4 x0 = Sv[0], x1 = Sv[1];
        a0.x = fmaf(w, x0.x, a0.x); a0.y = fmaf(w, x0.y, a0.y);
        a0.z = fmaf(w, x0.z, a0.z); a0.w = fmaf(w, x0.w, a0.w);
        a1.x = fmaf(w, x1.x, a1.x); a1.y = fmaf(w, x1.y, a1.y);
        a1.z = fmaf(w, x1.z, a1.z);
    }
    #pragma unroll
    for (int m = 1; m <= 2; m <<= 1) {
        a0.x += __shfl_xor(a0.x, m); a0.y += __shfl_xor(a0.y, m);
        a0.z += __shfl_xor(a0.z, m); a0.w += __shfl_xor(a0.w, m);
        a1.x += __shfl_xor(a1.x, m); a1.y += __shfl_xor(a1.y, m);
        a1.z += __shfl_xor(a1.z, m);
    }
    if (sub == 0) {
        float s2 = 2.f * (dir ? inv_in[node] : inv_out[node]);
        const float4* Xv = (const float4*)(X + (long)node * 8);
        float4 x0 = Xv[0], x1 = Xv[1];
        float* T = dir ? T2i : T2o;
        float4* Tv = (float4*)(T + (long)node * 8);
        Tv[0] = make_float4(fmaf(s2, a0.x, -x0.x), fmaf(s2, a0.y, -x0.y),
                            fmaf(s2, a0.z, -x0.z), fmaf(s2, a0.w, -x0.w));
        Tv[1] = make_float4(fmaf(s2, a1.x, -x1.x), fmaf(s2, a1.y, -x1.y),
                            fmaf(s2, a1.z, -x1.z), 0.f);
    }
}

// ====== node step: wave-uniform channel slices, scalar weight loads ========
// Block = 256 threads = 4 waves. Block handles 64 nodes (lane = node).
// Wave w computes channels [w*32, w*32+32); weights are wave-uniform ->
// compiler emits s_load into SGPRs (no per-lane memory in the inner loop).
__global__ __launch_bounds__(256) void node_step_kernel(
    const float* __restrict__ env, const float* __restrict__ night,
    const float* __restrict__ wzT, const float* __restrict__ whT,
    const float* __restrict__ linW, const float* __restrict__ linb,
    float* __restrict__ X,
    const float* __restrict__ Txo, const float* __restrict__ Txi,
    const float* __restrict__ T2o, const float* __restrict__ T2i,
    float* __restrict__ out, int t)
{
    __shared__ float red[4][64];
    int lane = threadIdx.x & 63;
    int wave = __builtin_amdgcn_readfirstlane(threadIdx.x >> 6);   // force SGPR
    int node = blockIdx.x * 64 + lane;
    int nc = node < Nn ? node : Nn - 1;   // clamp for loads; stores guarded

    float f[36];
    {
        const float* p;
        p = X   + (long)nc * 8;
        #pragma unroll
        for (int k = 0; k < 7; k++) f[k] = p[k];
        p = Txo + (long)nc * 8;
        #pragma unroll
        for (int k = 0; k < 7; k++) f[7 + k] = p[k];
        p = Txi + (long)nc * 8;
        #pragma unroll
        for (int k = 0; k < 7; k++) f[14 + k] = p[k];
        p = T2o + (long)nc * 8;
        #pragma unroll
        for (int k = 0; k < 7; k++) f[21 + k] = p[k];
        p = T2i + (long)nc * 8;
        #pragma unroll
        for (int k = 0; k < 7; k++) f[28 + k] = p[k];
        f[35] = 1.f;
    }

    int jbase = wave * 32;
    float acc = 0.f;
    for (int jj = 0; jj < 32; jj++) {
        int j = jbase + jj;                      // wave-uniform
        const float* __restrict__ wz = wzT + j * 36;
        const float* __restrict__ wh = whT + j * 36;
        float hz = 0.f, hh = 0.f;
        #pragma unroll
        for (int k = 0; k < 36; k++) {
            hz = fmaf(f[k], wz[k], hz);
            hh = fmaf(f[k], wh[k], hh);
        }
        float z  = 1.f / (1.f + __expf(-hz));
        float e2 = __expf(2.f * hh);
        float ht = 1.f - 2.f / (e2 + 1.f);       // tanh
        float hn = (1.f - z) * ht;               // (1-Z)*H~  (hid0 == 0)
        acc = fmaf(fmaxf(hn, 0.f), linW[j], acc);
    }
    red[wave][lane] = acc;
    __syncthreads();

    if (wave == 0 && node < Nn) {
        float o = red[0][lane] + red[1][lane] + red[2][lane] + red[3][lane] + linb[0];
        o *= night[(long)node * 13 + t + 1];
        out[(long)node * 13 + t + 1] = o;
        if (t + 1 < Tt) {
            X[(long)node * 8 + 0] = o;
            #pragma unroll
            for (int c = 0; c < 4; c++)
                X[(long)node * 8 + 1 + c] = env[(long)node * 48 + c * 12 + (t + 1)];
        }
    }
}

extern "C" void kernel_launch(void* const* d_in, const int* in_sizes, int n_in,
                              void* d_out, int out_size, void* d_ws, size_t ws_size,
                              hipStream_t stream) {
    const float* x      = (const float*)d_in[0];
    const float* env    = (const float*)d_in[1];
    const float* coords = (const float*)d_in[2];
    const int*   ei     = (const int*)d_in[3];
    const float* ew     = (const float*)d_in[4];
    const float* night  = (const float*)d_in[5];
    const float* Wz     = (const float*)d_in[6];
    const float* bz     = (const float*)d_in[7];
    // d_in[8]=Wr, d_in[9]=br unused (R gate never affects output)
    const float* Wh     = (const float*)d_in[10];
    const float* bh     = (const float*)d_in[11];
    const float* linW   = (const float*)d_in[12];
    const float* linb   = (const float*)d_in[13];
    float* out = (float*)d_out;

    float* w = (float*)d_ws;
    float* X       = w;                   // N x 8
    float* Txo     = w + 400000;
    float* Txi     = w + 800000;
    float* T2o     = w + 1200000;
    float* T2i     = w + 1600000;
    float* inv_out = w + 2000000;         // N
    float* inv_in  = w + 2050000;
    float* wzT     = w + 2100000;         // 128*36
    float* whT     = w + 2104608;
    int* cntR      = (int*)(w + 2109216); // N
    int* cntC      = cntR + 50000;
    int* rowptrR   = cntC + 50000;        // N+1
    int* rowptrC   = rowptrR + 50001;
    int* nextR     = rowptrC + 50001;     // N
    int* nextC     = nextR + 50000;
    unsigned* adjR = (unsigned*)(nextC + 50000);  // E x 4B
    unsigned* adjC = adjR + Ee;

    // ---- CSR build (per launch; ws is re-poisoned every call) ----
    hipMemsetAsync(cntR, 0, 2 * Nn * sizeof(int), stream);
    hist_kernel<<<(Ee + 255) / 256, 256, 0, stream>>>(ei, cntR, cntC);
    scan_kernel<<<1, 1024, 0, stream>>>(cntR, rowptrR, nextR);
    scan_kernel<<<1, 1024, 0, stream>>>(cntC, rowptrC, nextC);
    scatter_kernel<<<(Ee + 255) / 256, 256, 0, stream>>>(ei, ew, nextR, nextC, adjR, adjC);

    weff_kernel<<<(2 * 128 * 36 + 255) / 256, 256, 0, stream>>>(Wz, Wh, bz, bh, wzT, whT);
    init_kernel<<<(Nn + 255) / 256, 256, 0, stream>>>(x, env, coords, X, out);

    for (int t = 0; t < Tt; t++) {
        gather1_kernel<<<(Nn * 8 + 255) / 256, 256, 0, stream>>>(
            rowptrR, adjR, rowptrC, adjC, X, Txo, Txi, inv_out, inv_in);
        gather2_kernel<<<(Nn * 8 + 255) / 256, 256, 0, stream>>>(
            rowptrR, adjR, rowptrC, adjC, X, Txo, Txi, inv_out, inv_in, T2o, T2i);
        node_step_kernel<<<(Nn + 63) / 64, 256, 0, stream>>>(
            env, night, wzT, whT, linW, linb, X, Txo, Txi, T2o, T2i, out, t);
    }
}

// Round 4
// 1070.472 us; speedup vs baseline: 14.4690x; 1.1368x over previous
//
#include <hip/hip_runtime.h>
#include <hip/hip_fp16.h>

#define Nn 50000
#define Ee 800000
#define Tt 12
#define NBAND 8
#define BAND 6250        // Nn / NBAND exactly
#define NSB 32           // nodes per node_step block-chunk
#define NCHUNKS ((Nn + NSB - 1) / NSB)   // 1563
// HID=128, K=3, F_IN=7, effective features = 35 (+1 bias slot)
// All node feature rows stored as 8 x f16 = 16 B (one dwordx4 gather).
// Adjacency entry: (src_node << 16) | half_bits(edge_weight) -- 4 bytes.

// =================== CSR build (once per launch) ===========================
__global__ __launch_bounds__(256) void hist_kernel(
    const int* __restrict__ ei, int* __restrict__ cntR, int* __restrict__ cntC)
{
    int e = blockIdx.x * 256 + threadIdx.x;
    if (e >= Ee) return;
    atomicAdd(&cntR[ei[e]], 1);
    atomicAdd(&cntC[ei[Ee + e]], 1);
}

__global__ __launch_bounds__(1024) void scan_kernel(
    const int* __restrict__ cnt, int* __restrict__ rowptr, int* __restrict__ nextp)
{
    __shared__ int part[1024];
    int t = threadIdx.x;
    const int chunk = (Nn + 1023) / 1024;   // 49
    int lo = t * chunk;
    int hi = min(lo + chunk, Nn);
    int s = 0;
    for (int i = lo; i < hi; i++) s += cnt[i];
    part[t] = s;
    __syncthreads();
    for (int off = 1; off < 1024; off <<= 1) {
        int v = (t >= off) ? part[t - off] : 0;
        __syncthreads();
        part[t] += v;
        __syncthreads();
    }
    int base = (t == 0) ? 0 : part[t - 1];
    for (int i = lo; i < hi; i++) { rowptr[i] = base; nextp[i] = base; base += cnt[i]; }
    if (t == 1023) rowptr[Nn] = part[1023];
}

// Banded scatter: block handles destination band (blockIdx & 7); with the
// blockIdx%8 -> XCD round-robin, each band's 400 KB write region stays hot in
// one L2 so lines fill before writeback (kills the 105 MB write amplification).
__global__ __launch_bounds__(256) void scatter_banded(
    const int* __restrict__ ei, const float* __restrict__ ew,
    int* __restrict__ nextR, int* __restrict__ nextC,
    unsigned* __restrict__ adjR, unsigned* __restrict__ adjC)
{
    int band = blockIdx.x & (NBAND - 1);
    int chunk = blockIdx.x >> 3;
    int lo = band * BAND, hi = lo + BAND;
    int stride = (gridDim.x >> 3) * 256;
    for (int e = chunk * 256 + threadIdx.x; e < Ee; e += stride) {
        int r = ei[e], c = ei[Ee + e];
        bool wr = (r >= lo && r < hi);
        bool wc = (c >= lo && c < hi);
        if (!(wr || wc)) continue;
        unsigned wb = __half_as_ushort(__float2half(ew[e]));
        if (wr) adjR[atomicAdd(&nextR[r], 1)] = ((unsigned)c << 16) | wb;
        if (wc) adjC[atomicAdd(&nextC[c], 1)] = ((unsigned)r << 16) | wb;
    }
}

// ==== effective weights, layout [gate][k*128 + j], k=35 is the bias row ====
// f layout: [0..6]=X, [7..13]=Tx_o, [14..20]=Tx_i, [21..27]=Tx_o2, [28..34]=Tx_i2, [35]=1
__global__ __launch_bounds__(256) void weff_kernel(
    const float* __restrict__ Wz, const float* __restrict__ Wh,
    const float* __restrict__ bz, const float* __restrict__ bh,
    float* __restrict__ wzT, float* __restrict__ whT)
{
    int idx = blockIdx.x * 256 + threadIdx.x;
    if (idx >= 2 * 36 * 128) return;
    const float* W = (idx < 36 * 128) ? Wz : Wh;
    const float* B = (idx < 36 * 128) ? bz : bh;
    float* O       = (idx < 36 * 128) ? wzT : whT;
    int rem = idx % (36 * 128);
    int k = rem / 128, j = rem % 128;
    float v;
    if (k == 35) v = B[j];
    else {
        int p = k / 7, rr = k % 7;
        // W flat: ((d*3 + kk)*135 + rr)*128 + j
        if (p == 0)      v = W[(0 * 135 + rr) * 128 + j] + W[(3 * 135 + rr) * 128 + j];
        else if (p == 1) v = W[(1 * 135 + rr) * 128 + j];
        else if (p == 2) v = W[(4 * 135 + rr) * 128 + j];
        else if (p == 3) v = W[(2 * 135 + rr) * 128 + j];
        else             v = W[(5 * 135 + rr) * 128 + j];
    }
    O[k * 128 + j] = v;
}

// =================== init: Xh row (f16) and out column 0 ===================
__global__ __launch_bounds__(256) void init_kernel(
    const float* __restrict__ x, const float* __restrict__ env,
    const float* __restrict__ coords, __half* __restrict__ Xh,
    float* __restrict__ out)
{
    int i = blockIdx.x * 256 + threadIdx.x;
    if (i >= Nn) return;
    float xv = x[i * Tt];
    __half* r = Xh + (long)i * 8;
    r[0] = __float2half(xv);
    #pragma unroll
    for (int c = 0; c < 4; c++) r[1 + c] = __float2half(env[i * 48 + c * 12]);
    r[5] = __float2half(coords[i * 2 + 0]);
    r[6] = __float2half(coords[i * 2 + 1]);
    r[7] = __half(0.f);
    out[i * 13 + 0] = xv;
}

__device__ __forceinline__ void unpack8(const __half* p, float* v) {
    uint4 hv = *((const uint4*)p);
    float2 p0 = __half22float2(*(__half2*)&hv.x);
    float2 p1 = __half22float2(*(__half2*)&hv.y);
    float2 p2 = __half22float2(*(__half2*)&hv.z);
    float2 p3 = __half22float2(*(__half2*)&hv.w);
    v[0] = p0.x; v[1] = p0.y; v[2] = p1.x; v[3] = p1.y;
    v[4] = p2.x; v[5] = p2.y; v[6] = p3.x;
}

__device__ __forceinline__ void pack8(__half* p, const float* v) {
    __half2 q0 = __floats2half2_rn(v[0], v[1]);
    __half2 q1 = __floats2half2_rn(v[2], v[3]);
    __half2 q2 = __floats2half2_rn(v[4], v[5]);
    __half2 q3 = __floats2half2_rn(v[6], 0.f);
    uint4 st;
    st.x = *(unsigned*)&q0; st.y = *(unsigned*)&q1;
    st.z = *(unsigned*)&q2; st.w = *(unsigned*)&q3;
    *((uint4*)p) = st;
}

// ============== gather pass 1: Tx = inv * segsum(w * Xh[src]) ==============
// 8 threads per node: bit2 = dir (out/in), bits0-1 = sub.
__global__ __launch_bounds__(256) void gather1_kernel(
    const int* __restrict__ rowptrR, const unsigned* __restrict__ adjR,
    const int* __restrict__ rowptrC, const unsigned* __restrict__ adjC,
    const __half* __restrict__ Xh,
    __half* __restrict__ TxoH, __half* __restrict__ TxiH,
    float* __restrict__ inv_out, float* __restrict__ inv_in)
{
    int tid = blockIdx.x * 256 + threadIdx.x;
    if (tid >= Nn * 8) return;
    int node = tid >> 3;
    int dir = (tid >> 2) & 1, sub = tid & 3;
    const int*      rp  = dir ? rowptrC : rowptrR;
    const unsigned* adj = dir ? adjC : adjR;
    int b = rp[node], e = rp[node + 1];
    float a[7] = {0.f, 0.f, 0.f, 0.f, 0.f, 0.f, 0.f};
    float sw = 0.f;
    for (int k = b + sub; k < e; k += 4) {
        unsigned ed = adj[k];
        float w = __half2float(__ushort_as_half((unsigned short)(ed & 0xffffu)));
        float xv[7];
        unpack8(Xh + (long)(ed >> 16) * 8, xv);
        #pragma unroll
        for (int q = 0; q < 7; q++) a[q] = fmaf(w, xv[q], a[q]);
        sw += w;
    }
    #pragma unroll
    for (int m = 1; m <= 2; m <<= 1) {
        #pragma unroll
        for (int q = 0; q < 7; q++) a[q] += __shfl_xor(a[q], m);
        sw += __shfl_xor(sw, m);
    }
    if (sub == 0) {
        float inv = sw > 0.f ? 1.f / sw : 0.f;
        (dir ? inv_in : inv_out)[node] = inv;
        #pragma unroll
        for (int q = 0; q < 7; q++) a[q] *= inv;
        pack8((dir ? TxiH : TxoH) + (long)node * 8, a);
    }
}

// ======= gather pass 2: T2 = 2*inv*segsum(w * Tx[src]) - X[node] ===========
__global__ __launch_bounds__(256) void gather2_kernel(
    const int* __restrict__ rowptrR, const unsigned* __restrict__ adjR,
    const int* __restrict__ rowptrC, const unsigned* __restrict__ adjC,
    const __half* __restrict__ Xh,
    const __half* __restrict__ TxoH, const __half* __restrict__ TxiH,
    const float* __restrict__ inv_out, const float* __restrict__ inv_in,
    __half* __restrict__ T2oH, __half* __restrict__ T2iH)
{
    int tid = blockIdx.x * 256 + threadIdx.x;
    if (tid >= Nn * 8) return;
    int node = tid >> 3;
    int dir = (tid >> 2) & 1, sub = tid & 3;
    const int*      rp  = dir ? rowptrC : rowptrR;
    const unsigned* adj = dir ? adjC : adjR;
    const __half*   src = dir ? TxiH : TxoH;
    int b = rp[node], e = rp[node + 1];
    float a[7] = {0.f, 0.f, 0.f, 0.f, 0.f, 0.f, 0.f};
    for (int k = b + sub; k < e; k += 4) {
        unsigned ed = adj[k];
        float w = __half2float(__ushort_as_half((unsigned short)(ed & 0xffffu)));
        float xv[7];
        unpack8(src + (long)(ed >> 16) * 8, xv);
        #pragma unroll
        for (int q = 0; q < 7; q++) a[q] = fmaf(w, xv[q], a[q]);
    }
    #pragma unroll
    for (int m = 1; m <= 2; m <<= 1) {
        #pragma unroll
        for (int q = 0; q < 7; q++) a[q] += __shfl_xor(a[q], m);
    }
    if (sub == 0) {
        float s2 = 2.f * (dir ? inv_in[node] : inv_out[node]);
        float xv[7];
        unpack8(Xh + (long)node * 8, xv);
        #pragma unroll
        for (int q = 0; q < 7; q++) a[q] = fmaf(s2, a[q], -xv[q]);
        pack8((dir ? T2iH : T2oH) + (long)node * 8, a);
    }
}

// ====== node step: channel-resident weights (72 VGPRs/lane), nodes in LDS ==
// Block = 4 waves. Waves 0/1: channels 0-63 / 64-127 for chunk nodes [0,16);
// waves 2/3: same for nodes [16,32). Inner loop = pure register FMA.
__global__ __launch_bounds__(256) void node_step_kernel(
    const float* __restrict__ env, const float* __restrict__ night,
    const float* __restrict__ wzT, const float* __restrict__ whT,
    const float* __restrict__ linW, const float* __restrict__ linb,
    __half* __restrict__ Xh,
    const __half* __restrict__ TxoH, const __half* __restrict__ TxiH,
    const __half* __restrict__ T2oH, const __half* __restrict__ T2iH,
    float* __restrict__ out, int t)
{
    __shared__ float f_s[NSB][36];
    __shared__ float part_s[2][NSB];
    int tid = threadIdx.x;
    int lane = tid & 63;
    int wave = tid >> 6;
    int chSel = wave & 1;
    int ch = chSel * 64 + lane;
    int half_id = wave >> 1;

    float wz[36], wh[36];
    #pragma unroll
    for (int k = 0; k < 36; k++) wz[k] = wzT[k * 128 + ch];
    #pragma unroll
    for (int k = 0; k < 36; k++) wh[k] = whT[k * 128 + ch];
    float lw = linW[ch];
    float lb = linb[0];

    for (int chunk = blockIdx.x; chunk < NCHUNKS; chunk += gridDim.x) {
        int base = chunk * NSB;
        __syncthreads();
        if (tid < NSB * 5) {
            int n = tid / 5, a = tid % 5;
            int node = base + n;
            int nc = node < Nn ? node : Nn - 1;
            const __half* src = a == 0 ? Xh : a == 1 ? TxoH : a == 2 ? TxiH
                              : a == 3 ? T2oH : T2iH;
            float v[7];
            unpack8(src + (long)nc * 8, v);
            float* d = &f_s[n][a * 7];
            #pragma unroll
            for (int q = 0; q < 7; q++) d[q] = v[q];
            if (a == 0) f_s[n][35] = 1.f;
        }
        __syncthreads();
        #pragma unroll 1
        for (int n = 0; n < 16; n++) {
            int ni = half_id * 16 + n;
            const float4* fv = (const float4*)f_s[ni];   // broadcast reads
            float hz = 0.f, hh = 0.f;
            #pragma unroll
            for (int q = 0; q < 9; q++) {
                float4 fq = fv[q];
                hz = fmaf(fq.x, wz[q*4+0], hz); hh = fmaf(fq.x, wh[q*4+0], hh);
                hz = fmaf(fq.y, wz[q*4+1], hz); hh = fmaf(fq.y, wh[q*4+1], hh);
                hz = fmaf(fq.z, wz[q*4+2], hz); hh = fmaf(fq.z, wh[q*4+2], hh);
                hz = fmaf(fq.w, wz[q*4+3], hz); hh = fmaf(fq.w, wh[q*4+3], hh);
            }
            float z  = 1.f / (1.f + __expf(-hz));
            float e2 = __expf(2.f * hh);
            float ht = 1.f - 2.f / (e2 + 1.f);           // tanh
            float v = fmaxf((1.f - z) * ht, 0.f) * lw;   // (1-Z)*H~, relu, lin
            v += __shfl_xor(v, 1);  v += __shfl_xor(v, 2);  v += __shfl_xor(v, 4);
            v += __shfl_xor(v, 8);  v += __shfl_xor(v, 16); v += __shfl_xor(v, 32);
            if (lane == 0) part_s[chSel][ni] = v;
        }
        __syncthreads();
        if (tid < NSB) {
            int node = base + tid;
            if (node < Nn) {
                float o = part_s[0][tid] + part_s[1][tid] + lb;
                o *= night[(long)node * 13 + t + 1];
                out[(long)node * 13 + t + 1] = o;
                if (t + 1 < Tt) {
                    __half* xr = Xh + (long)node * 8;
                    xr[0] = __float2half(o);
                    #pragma unroll
                    for (int c = 0; c < 4; c++)
                        xr[1 + c] = __float2half(env[(long)node * 48 + c * 12 + t + 1]);
                }
            }
        }
    }
}

extern "C" void kernel_launch(void* const* d_in, const int* in_sizes, int n_in,
                              void* d_out, int out_size, void* d_ws, size_t ws_size,
                              hipStream_t stream) {
    const float* x      = (const float*)d_in[0];
    const float* env    = (const float*)d_in[1];
    const float* coords = (const float*)d_in[2];
    const int*   ei     = (const int*)d_in[3];
    const float* ew     = (const float*)d_in[4];
    const float* night  = (const float*)d_in[5];
    const float* Wz     = (const float*)d_in[6];
    const float* bz     = (const float*)d_in[7];
    // d_in[8]=Wr, d_in[9]=br unused (R gate never affects output)
    const float* Wh     = (const float*)d_in[10];
    const float* bh     = (const float*)d_in[11];
    const float* linW   = (const float*)d_in[12];
    const float* linb   = (const float*)d_in[13];
    float* out = (float*)d_out;

    float* w = (float*)d_ws;
    float* wzT     = w;                     // 36*128
    float* whT     = w + 4608;
    float* inv_out = w + 9216;              // N
    float* inv_in  = w + 59216;
    __half* Xh   = (__half*)(w + 109216);   // N x 8 halves (16B-aligned offsets)
    __half* TxoH = (__half*)(w + 309216);
    __half* TxiH = (__half*)(w + 509216);
    __half* T2oH = (__half*)(w + 709216);
    __half* T2iH = (__half*)(w + 909216);
    int* cntR    = (int*)(w + 1109216);     // N
    int* cntC    = cntR + 50000;
    int* rowptrR = cntC + 50000;            // N+1
    int* rowptrC = rowptrR + 50001;
    int* nextR   = rowptrC + 50001;         // N
    int* nextC   = nextR + 50000;
    unsigned* adjR = (unsigned*)(nextC + 50000);   // E x 4B
    unsigned* adjC = adjR + Ee;

    // ---- CSR build (per launch; ws is re-poisoned every call) ----
    hipMemsetAsync(cntR, 0, 2 * Nn * sizeof(int), stream);
    hist_kernel<<<(Ee + 255) / 256, 256, 0, stream>>>(ei, cntR, cntC);
    scan_kernel<<<1, 1024, 0, stream>>>(cntR, rowptrR, nextR);
    scan_kernel<<<1, 1024, 0, stream>>>(cntC, rowptrC, nextC);
    scatter_banded<<<8 * 256, 256, 0, stream>>>(ei, ew, nextR, nextC, adjR, adjC);

    weff_kernel<<<(2 * 36 * 128 + 255) / 256, 256, 0, stream>>>(Wz, Wh, bz, bh, wzT, whT);
    init_kernel<<<(Nn + 255) / 256, 256, 0, stream>>>(x, env, coords, Xh, out);

    for (int t = 0; t < Tt; t++) {
        gather1_kernel<<<(Nn * 8 + 255) / 256, 256, 0, stream>>>(
            rowptrR, adjR, rowptrC, adjC, Xh, TxoH, TxiH, inv_out, inv_in);
        gather2_kernel<<<(Nn * 8 + 255) / 256, 256, 0, stream>>>(
            rowptrR, adjR, rowptrC, adjC, Xh, TxoH, TxiH, inv_out, inv_in, T2oH, T2iH);
        node_step_kernel<<<NCHUNKS, 256, 0, stream>>>(
            env, night, wzT, whT, linW, linb, Xh, TxoH, TxiH, T2oH, T2iH, out, t);
    }
}

// Round 5
// 859.462 us; speedup vs baseline: 18.0213x; 1.2455x over previous
//
#include <hip/hip_runtime.h>
#include <hip/hip_fp16.h>

#define Nn 50000
#define Ee 800000
#define Tt 12
#define NBAND 8
#define BAND 6250        // Nn / NBAND exactly
#define NSB 32           // nodes per node_step block-chunk
#define NCHUNKS ((Nn + NSB - 1) / NSB)   // 1563
#define SCB 196          // scan blocks per half: 196*256 >= Nn
// HID=128, K=3, F_IN=7, effective features = 35 (+1 bias slot)
// All node feature rows stored as 8 x f16 = 16 B (one dwordx4 gather).
// Adjacency entry: (src_node << 16) | half_bits(edge_weight) -- 4 bytes.

// =================== CSR build (once per launch) ===========================
__global__ __launch_bounds__(256) void hist_kernel(
    const int* __restrict__ ei, int* __restrict__ cntR, int* __restrict__ cntC)
{
    int e = blockIdx.x * 256 + threadIdx.x;
    if (e >= Ee) return;
    atomicAdd(&cntR[ei[e]], 1);
    atomicAdd(&cntC[ei[Ee + e]], 1);
}

// ---- 3-phase multi-block exclusive scan of cntR / cntC --------------------
__global__ __launch_bounds__(256) void scanA_kernel(
    const int* __restrict__ cntR, const int* __restrict__ cntC,
    int* __restrict__ bsum)
{
    const int* cnt = blockIdx.y ? cntC : cntR;
    int i = blockIdx.x * 256 + threadIdx.x;
    int v = (i < Nn) ? cnt[i] : 0;
    __shared__ int ws_[4];
    v += __shfl_xor(v, 1);  v += __shfl_xor(v, 2);  v += __shfl_xor(v, 4);
    v += __shfl_xor(v, 8);  v += __shfl_xor(v, 16); v += __shfl_xor(v, 32);
    if ((threadIdx.x & 63) == 0) ws_[threadIdx.x >> 6] = v;
    __syncthreads();
    if (threadIdx.x == 0)
        bsum[blockIdx.y * 256 + blockIdx.x] = ws_[0] + ws_[1] + ws_[2] + ws_[3];
}

__global__ __launch_bounds__(256) void scanB_kernel(
    const int* __restrict__ bsum, int* __restrict__ bbase)
{
    int y = blockIdx.x;
    __shared__ int s[256];
    int t = threadIdx.x;
    int v = (t < SCB) ? bsum[y * 256 + t] : 0;
    s[t] = v;
    __syncthreads();
    for (int off = 1; off < 256; off <<= 1) {
        int u = (t >= off) ? s[t - off] : 0;
        __syncthreads();
        s[t] += u;
        __syncthreads();
    }
    bbase[y * 256 + t] = s[t] - v;   // exclusive
}

__global__ __launch_bounds__(256) void scanC_kernel(
    const int* __restrict__ cntR, const int* __restrict__ cntC,
    const int* __restrict__ bbase,
    int* __restrict__ startR, int* __restrict__ startC,
    int* __restrict__ nextR, int* __restrict__ nextC)
{
    int y = blockIdx.y;
    const int* cnt = y ? cntC : cntR;
    int* start     = y ? startC : startR;
    int* nxt       = y ? nextC : nextR;
    int i = blockIdx.x * 256 + threadIdx.x;
    int v = (i < Nn) ? cnt[i] : 0;
    __shared__ int s[256];
    int t = threadIdx.x;
    s[t] = v;
    __syncthreads();
    for (int off = 1; off < 256; off <<= 1) {
        int u = (t >= off) ? s[t - off] : 0;
        __syncthreads();
        s[t] += u;
        __syncthreads();
    }
    int st = bbase[y * 256 + blockIdx.x] + s[t] - v;
    if (i < Nn) { start[i] = st; nxt[i] = st; }
}

// Banded scatter: block handles destination band (blockIdx & 7); with the
// blockIdx%8 -> XCD round-robin, each band's write region stays L2-hot so
// lines fill before writeback (kills the 105 MB write amplification).
__global__ __launch_bounds__(256) void scatter_banded(
    const int* __restrict__ ei, const float* __restrict__ ew,
    int* __restrict__ nextR, int* __restrict__ nextC,
    unsigned* __restrict__ adjR, unsigned* __restrict__ adjC)
{
    int band = blockIdx.x & (NBAND - 1);
    int chunk = blockIdx.x >> 3;
    int lo = band * BAND, hi = lo + BAND;
    int stride = (gridDim.x >> 3) * 256;
    for (int e = chunk * 256 + threadIdx.x; e < Ee; e += stride) {
        int r = ei[e], c = ei[Ee + e];
        bool wr = (r >= lo && r < hi);
        bool wc = (c >= lo && c < hi);
        if (!(wr || wc)) continue;
        unsigned wb = __half_as_ushort(__float2half(ew[e]));
        if (wr) adjR[atomicAdd(&nextR[r], 1)] = ((unsigned)c << 16) | wb;
        if (wc) adjC[atomicAdd(&nextC[c], 1)] = ((unsigned)r << 16) | wb;
    }
}

// ==== effective weights, layout [gate][k*128 + j], k=35 is the bias row ====
// f layout: [0..6]=X, [7..13]=Tx_o, [14..20]=Tx_i, [21..27]=Tx_o2, [28..34]=Tx_i2, [35]=1
__global__ __launch_bounds__(256) void weff_kernel(
    const float* __restrict__ Wz, const float* __restrict__ Wh,
    const float* __restrict__ bz, const float* __restrict__ bh,
    float* __restrict__ wzT, float* __restrict__ whT)
{
    int idx = blockIdx.x * 256 + threadIdx.x;
    if (idx >= 2 * 36 * 128) return;
    const float* W = (idx < 36 * 128) ? Wz : Wh;
    const float* B = (idx < 36 * 128) ? bz : bh;
    float* O       = (idx < 36 * 128) ? wzT : whT;
    int rem = idx % (36 * 128);
    int k = rem / 128, j = rem % 128;
    float v;
    if (k == 35) v = B[j];
    else {
        int p = k / 7, rr = k % 7;
        // W flat: ((d*3 + kk)*135 + rr)*128 + j
        if (p == 0)      v = W[(0 * 135 + rr) * 128 + j] + W[(3 * 135 + rr) * 128 + j];
        else if (p == 1) v = W[(1 * 135 + rr) * 128 + j];
        else if (p == 2) v = W[(4 * 135 + rr) * 128 + j];
        else if (p == 3) v = W[(2 * 135 + rr) * 128 + j];
        else             v = W[(5 * 135 + rr) * 128 + j];
    }
    O[k * 128 + j] = v;
}

// =================== init: Xh row (f16) and out column 0 ===================
__global__ __launch_bounds__(256) void init_kernel(
    const float* __restrict__ x, const float* __restrict__ env,
    const float* __restrict__ coords, __half* __restrict__ Xh,
    float* __restrict__ out)
{
    int i = blockIdx.x * 256 + threadIdx.x;
    if (i >= Nn) return;
    float xv = x[i * Tt];
    __half* r = Xh + (long)i * 8;
    r[0] = __float2half(xv);
    #pragma unroll
    for (int c = 0; c < 4; c++) r[1 + c] = __float2half(env[i * 48 + c * 12]);
    r[5] = __float2half(coords[i * 2 + 0]);
    r[6] = __float2half(coords[i * 2 + 1]);
    r[7] = __half(0.f);
    out[i * 13 + 0] = xv;
}

__device__ __forceinline__ void unpack8(const __half* p, float* v) {
    uint4 hv = *((const uint4*)p);
    float2 p0 = __half22float2(*(__half2*)&hv.x);
    float2 p1 = __half22float2(*(__half2*)&hv.y);
    float2 p2 = __half22float2(*(__half2*)&hv.z);
    float2 p3 = __half22float2(*(__half2*)&hv.w);
    v[0] = p0.x; v[1] = p0.y; v[2] = p1.x; v[3] = p1.y;
    v[4] = p2.x; v[5] = p2.y; v[6] = p3.x;
}

__device__ __forceinline__ void pack8(__half* p, const float* v) {
    __half2 q0 = __floats2half2_rn(v[0], v[1]);
    __half2 q1 = __floats2half2_rn(v[2], v[3]);
    __half2 q2 = __floats2half2_rn(v[4], v[5]);
    __half2 q3 = __floats2half2_rn(v[6], 0.f);
    uint4 st;
    st.x = *(unsigned*)&q0; st.y = *(unsigned*)&q1;
    st.z = *(unsigned*)&q2; st.w = *(unsigned*)&q3;
    *((uint4*)p) = st;
}

// ============== gather pass 1: Tx = inv * segsum(w * Xh[src]) ==============
// 8 threads per node: bit2 = dir (out/in), bits0-1 = sub.
__global__ __launch_bounds__(256) void gather1_kernel(
    const int* __restrict__ startR, const int* __restrict__ cntR,
    const unsigned* __restrict__ adjR,
    const int* __restrict__ startC, const int* __restrict__ cntC,
    const unsigned* __restrict__ adjC,
    const __half* __restrict__ Xh,
    __half* __restrict__ TxoH, __half* __restrict__ TxiH,
    float* __restrict__ inv_out, float* __restrict__ inv_in)
{
    int tid = blockIdx.x * 256 + threadIdx.x;
    if (tid >= Nn * 8) return;
    int node = tid >> 3;
    int dir = (tid >> 2) & 1, sub = tid & 3;
    const int*      st  = dir ? startC : startR;
    const int*      cn  = dir ? cntC : cntR;
    const unsigned* adj = dir ? adjC : adjR;
    int b = st[node], e = b + cn[node];
    float a[7] = {0.f, 0.f, 0.f, 0.f, 0.f, 0.f, 0.f};
    float sw = 0.f;
    for (int k = b + sub; k < e; k += 4) {
        unsigned ed = adj[k];
        float w = __half2float(__ushort_as_half((unsigned short)(ed & 0xffffu)));
        float xv[7];
        unpack8(Xh + (long)(ed >> 16) * 8, xv);
        #pragma unroll
        for (int q = 0; q < 7; q++) a[q] = fmaf(w, xv[q], a[q]);
        sw += w;
    }
    #pragma unroll
    for (int m = 1; m <= 2; m <<= 1) {
        #pragma unroll
        for (int q = 0; q < 7; q++) a[q] += __shfl_xor(a[q], m);
        sw += __shfl_xor(sw, m);
    }
    if (sub == 0) {
        float inv = sw > 0.f ? 1.f / sw : 0.f;
        (dir ? inv_in : inv_out)[node] = inv;
        #pragma unroll
        for (int q = 0; q < 7; q++) a[q] *= inv;
        pack8((dir ? TxiH : TxoH) + (long)node * 8, a);
    }
}

// ======= gather pass 2: T2 = 2*inv*segsum(w * Tx[src]) - X[node] ===========
__global__ __launch_bounds__(256) void gather2_kernel(
    const int* __restrict__ startR, const int* __restrict__ cntR,
    const unsigned* __restrict__ adjR,
    const int* __restrict__ startC, const int* __restrict__ cntC,
    const unsigned* __restrict__ adjC,
    const __half* __restrict__ Xh,
    const __half* __restrict__ TxoH, const __half* __restrict__ TxiH,
    const float* __restrict__ inv_out, const float* __restrict__ inv_in,
    __half* __restrict__ T2oH, __half* __restrict__ T2iH)
{
    int tid = blockIdx.x * 256 + threadIdx.x;
    if (tid >= Nn * 8) return;
    int node = tid >> 3;
    int dir = (tid >> 2) & 1, sub = tid & 3;
    const int*      st  = dir ? startC : startR;
    const int*      cn  = dir ? cntC : cntR;
    const unsigned* adj = dir ? adjC : adjR;
    const __half*   src = dir ? TxiH : TxoH;
    int b = st[node], e = b + cn[node];
    float a[7] = {0.f, 0.f, 0.f, 0.f, 0.f, 0.f, 0.f};
    for (int k = b + sub; k < e; k += 4) {
        unsigned ed = adj[k];
        float w = __half2float(__ushort_as_half((unsigned short)(ed & 0xffffu)));
        float xv[7];
        unpack8(src + (long)(ed >> 16) * 8, xv);
        #pragma unroll
        for (int q = 0; q < 7; q++) a[q] = fmaf(w, xv[q], a[q]);
    }
    #pragma unroll
    for (int m = 1; m <= 2; m <<= 1) {
        #pragma unroll
        for (int q = 0; q < 7; q++) a[q] += __shfl_xor(a[q], m);
    }
    if (sub == 0) {
        float s2 = 2.f * (dir ? inv_in[node] : inv_out[node]);
        float xv[7];
        unpack8(Xh + (long)node * 8, xv);
        #pragma unroll
        for (int q = 0; q < 7; q++) a[q] = fmaf(s2, a[q], -xv[q]);
        pack8((dir ? T2iH : T2oH) + (long)node * 8, a);
    }
}

// ====== node step: channel-resident weights (72 VGPRs/lane), nodes in LDS ==
// Block = 4 waves. Waves 0/1: channels 0-63 / 64-127 for chunk nodes [0,16);
// waves 2/3: same for nodes [16,32). Inner loop = pure register FMA.
__global__ __launch_bounds__(256) void node_step_kernel(
    const float* __restrict__ env, const float* __restrict__ night,
    const float* __restrict__ wzT, const float* __restrict__ whT,
    const float* __restrict__ linW, const float* __restrict__ linb,
    __half* __restrict__ Xh,
    const __half* __restrict__ TxoH, const __half* __restrict__ TxiH,
    const __half* __restrict__ T2oH, const __half* __restrict__ T2iH,
    float* __restrict__ out, int t)
{
    __shared__ float f_s[NSB][36];
    __shared__ float part_s[2][NSB];
    int tid = threadIdx.x;
    int lane = tid & 63;
    int wave = tid >> 6;
    int chSel = wave & 1;
    int ch = chSel * 64 + lane;
    int half_id = wave >> 1;

    float wz[36], wh[36];
    #pragma unroll
    for (int k = 0; k < 36; k++) wz[k] = wzT[k * 128 + ch];
    #pragma unroll
    for (int k = 0; k < 36; k++) wh[k] = whT[k * 128 + ch];
    float lw = linW[ch];
    float lb = linb[0];

    for (int chunk = blockIdx.x; chunk < NCHUNKS; chunk += gridDim.x) {
        int base = chunk * NSB;
        __syncthreads();
        if (tid < NSB * 5) {
            int n = tid / 5, a = tid % 5;
            int node = base + n;
            int nc = node < Nn ? node : Nn - 1;
            const __half* src = a == 0 ? Xh : a == 1 ? TxoH : a == 2 ? TxiH
                              : a == 3 ? T2oH : T2iH;
            float v[7];
            unpack8(src + (long)nc * 8, v);
            float* d = &f_s[n][a * 7];
            #pragma unroll
            for (int q = 0; q < 7; q++) d[q] = v[q];
            if (a == 0) f_s[n][35] = 1.f;
        }
        __syncthreads();
        #pragma unroll 1
        for (int n = 0; n < 16; n++) {
            int ni = half_id * 16 + n;
            const float4* fv = (const float4*)f_s[ni];   // broadcast reads
            float hz = 0.f, hh = 0.f;
            #pragma unroll
            for (int q = 0; q < 9; q++) {
                float4 fq = fv[q];
                hz = fmaf(fq.x, wz[q*4+0], hz); hh = fmaf(fq.x, wh[q*4+0], hh);
                hz = fmaf(fq.y, wz[q*4+1], hz); hh = fmaf(fq.y, wh[q*4+1], hh);
                hz = fmaf(fq.z, wz[q*4+2], hz); hh = fmaf(fq.z, wh[q*4+2], hh);
                hz = fmaf(fq.w, wz[q*4+3], hz); hh = fmaf(fq.w, wh[q*4+3], hh);
            }
            float z  = 1.f / (1.f + __expf(-hz));
            float e2 = __expf(2.f * hh);
            float ht = 1.f - 2.f / (e2 + 1.f);           // tanh
            float v = fmaxf((1.f - z) * ht, 0.f) * lw;   // (1-Z)*H~, relu, lin
            v += __shfl_xor(v, 1);  v += __shfl_xor(v, 2);  v += __shfl_xor(v, 4);
            v += __shfl_xor(v, 8);  v += __shfl_xor(v, 16); v += __shfl_xor(v, 32);
            if (lane == 0) part_s[chSel][ni] = v;
        }
        __syncthreads();
        if (tid < NSB) {
            int node = base + tid;
            if (node < Nn) {
                float o = part_s[0][tid] + part_s[1][tid] + lb;
                o *= night[(long)node * 13 + t + 1];
                out[(long)node * 13 + t + 1] = o;
                if (t + 1 < Tt) {
                    __half* xr = Xh + (long)node * 8;
                    xr[0] = __float2half(o);
                    #pragma unroll
                    for (int c = 0; c < 4; c++)
                        xr[1 + c] = __float2half(env[(long)node * 48 + c * 12 + t + 1]);
                }
            }
        }
    }
}

extern "C" void kernel_launch(void* const* d_in, const int* in_sizes, int n_in,
                              void* d_out, int out_size, void* d_ws, size_t ws_size,
                              hipStream_t stream) {
    const float* x      = (const float*)d_in[0];
    const float* env    = (const float*)d_in[1];
    const float* coords = (const float*)d_in[2];
    const int*   ei     = (const int*)d_in[3];
    const float* ew     = (const float*)d_in[4];
    const float* night  = (const float*)d_in[5];
    const float* Wz     = (const float*)d_in[6];
    const float* bz     = (const float*)d_in[7];
    // d_in[8]=Wr, d_in[9]=br unused (R gate never affects output)
    const float* Wh     = (const float*)d_in[10];
    const float* bh     = (const float*)d_in[11];
    const float* linW   = (const float*)d_in[12];
    const float* linb   = (const float*)d_in[13];
    float* out = (float*)d_out;

    float* w = (float*)d_ws;
    float* wzT     = w;                     // 36*128
    float* whT     = w + 4608;
    float* inv_out = w + 9216;              // N
    float* inv_in  = w + 59216;
    __half* Xh   = (__half*)(w + 109216);   // N x 8 halves (16B-aligned offsets)
    __half* TxoH = (__half*)(w + 309216);
    __half* TxiH = (__half*)(w + 509216);
    __half* T2oH = (__half*)(w + 709216);
    __half* T2iH = (__half*)(w + 909216);
    int* cntR    = (int*)(w + 1109216);     // N
    int* cntC    = cntR + 50000;
    int* startR  = cntC + 50000;            // N
    int* startC  = startR + 50000;
    int* nextR   = startC + 50000;          // N
    int* nextC   = nextR + 50000;
    int* bsum    = nextC + 50000;           // 2 x 256
    int* bbase   = bsum + 512;              // 2 x 256
    unsigned* adjR = (unsigned*)(bbase + 512);   // E x 4B
    unsigned* adjC = adjR + Ee;

    // ---- CSR build (per launch; ws is re-poisoned every call) ----
    hipMemsetAsync(cntR, 0, 2 * Nn * sizeof(int), stream);
    hist_kernel<<<(Ee + 255) / 256, 256, 0, stream>>>(ei, cntR, cntC);
    scanA_kernel<<<dim3(SCB, 2), 256, 0, stream>>>(cntR, cntC, bsum);
    scanB_kernel<<<2, 256, 0, stream>>>(bsum, bbase);
    scanC_kernel<<<dim3(SCB, 2), 256, 0, stream>>>(
        cntR, cntC, bbase, startR, startC, nextR, nextC);
    scatter_banded<<<8 * 256, 256, 0, stream>>>(ei, ew, nextR, nextC, adjR, adjC);

    weff_kernel<<<(2 * 36 * 128 + 255) / 256, 256, 0, stream>>>(Wz, Wh, bz, bh, wzT, whT);
    init_kernel<<<(Nn + 255) / 256, 256, 0, stream>>>(x, env, coords, Xh, out);

    for (int t = 0; t < Tt; t++) {
        gather1_kernel<<<(Nn * 8 + 255) / 256, 256, 0, stream>>>(
            startR, cntR, adjR, startC, cntC, adjC, Xh, TxoH, TxiH, inv_out, inv_in);
        gather2_kernel<<<(Nn * 8 + 255) / 256, 256, 0, stream>>>(
            startR, cntR, adjR, startC, cntC, adjC, Xh, TxoH, TxiH,
            inv_out, inv_in, T2oH, T2iH);
        node_step_kernel<<<NCHUNKS, 256, 0, stream>>>(
            env, night, wzT, whT, linW, linb, Xh, TxoH, TxiH, T2oH, T2iH, out, t);
    }
}

// Round 6
// 815.327 us; speedup vs baseline: 18.9969x; 1.0541x over previous
//
#include <hip/hip_runtime.h>
#include <hip/hip_fp16.h>

#define Nn 50000
#define Ee 800000
#define Tt 12
#define NBAND 8
#define BAND 6250        // Nn / NBAND exactly
#define SCB 196          // scan blocks per half: 196*256 >= Nn
// HID=128, K=3, F_IN=7, effective features = 35 (+1 bias slot)
// Node feature rows: 8 x f16 = 16 B (one dwordx4 gather).
// Packed edge record (8 B): {lo = (c<<16)|wb, hi = (r<<16)|wb}, wb = f16(w).
// adjR entry = lo (keyed by r), adjC entry = hi (keyed by c).

// ============ pack edges + degree histogram (one pass over edges) ==========
__global__ __launch_bounds__(256) void pack_hist_kernel(
    const int* __restrict__ ei, const float* __restrict__ ew,
    uint2* __restrict__ packed, int* __restrict__ cntR, int* __restrict__ cntC)
{
    int e = blockIdx.x * 256 + threadIdx.x;
    if (e >= Ee) return;
    int r = ei[e], c = ei[Ee + e];
    unsigned wb = __half_as_ushort(__float2half(ew[e]));
    packed[e] = make_uint2(((unsigned)c << 16) | wb, ((unsigned)r << 16) | wb);
    atomicAdd(&cntR[r], 1);
    atomicAdd(&cntC[c], 1);
}

// ---- 3-phase multi-block exclusive scan of cntR / cntC --------------------
__global__ __launch_bounds__(256) void scanA_kernel(
    const int* __restrict__ cntR, const int* __restrict__ cntC,
    int* __restrict__ bsum)
{
    const int* cnt = blockIdx.y ? cntC : cntR;
    int i = blockIdx.x * 256 + threadIdx.x;
    int v = (i < Nn) ? cnt[i] : 0;
    __shared__ int ws_[4];
    v += __shfl_xor(v, 1);  v += __shfl_xor(v, 2);  v += __shfl_xor(v, 4);
    v += __shfl_xor(v, 8);  v += __shfl_xor(v, 16); v += __shfl_xor(v, 32);
    if ((threadIdx.x & 63) == 0) ws_[threadIdx.x >> 6] = v;
    __syncthreads();
    if (threadIdx.x == 0)
        bsum[blockIdx.y * 256 + blockIdx.x] = ws_[0] + ws_[1] + ws_[2] + ws_[3];
}

__global__ __launch_bounds__(256) void scanB_kernel(
    const int* __restrict__ bsum, int* __restrict__ bbase)
{
    int y = blockIdx.x;
    __shared__ int s[256];
    int t = threadIdx.x;
    int v = (t < SCB) ? bsum[y * 256 + t] : 0;
    s[t] = v;
    __syncthreads();
    for (int off = 1; off < 256; off <<= 1) {
        int u = (t >= off) ? s[t - off] : 0;
        __syncthreads();
        s[t] += u;
        __syncthreads();
    }
    bbase[y * 256 + t] = s[t] - v;   // exclusive
}

__global__ __launch_bounds__(256) void scanC_kernel(
    const int* __restrict__ cntR, const int* __restrict__ cntC,
    const int* __restrict__ bbase,
    int* __restrict__ startR, int* __restrict__ startC,
    int* __restrict__ nextR, int* __restrict__ nextC)
{
    int y = blockIdx.y;
    const int* cnt = y ? cntC : cntR;
    int* start     = y ? startC : startR;
    int* nxt       = y ? nextC : nextR;
    int i = blockIdx.x * 256 + threadIdx.x;
    int v = (i < Nn) ? cnt[i] : 0;
    __shared__ int s[256];
    int t = threadIdx.x;
    s[t] = v;
    __syncthreads();
    for (int off = 1; off < 256; off <<= 1) {
        int u = (t >= off) ? s[t - off] : 0;
        __syncthreads();
        s[t] += u;
        __syncthreads();
    }
    int st = bbase[y * 256 + blockIdx.x] + s[t] - v;
    if (i < Nn) { start[i] = st; nxt[i] = st; }
}

// Banded scatter: block handles destination band (blockIdx & 7); with the
// blockIdx%8 -> XCD round-robin each band's write region stays L2-hot so
// lines fill before writeback.
__global__ __launch_bounds__(256) void scatter_banded(
    const uint2* __restrict__ packed,
    int* __restrict__ nextR, int* __restrict__ nextC,
    unsigned* __restrict__ adjR, unsigned* __restrict__ adjC)
{
    int band = blockIdx.x & (NBAND - 1);
    int chunk = blockIdx.x >> 3;
    int lo = band * BAND, hi = lo + BAND;
    int stride = (gridDim.x >> 3) * 256;
    for (int e = chunk * 256 + threadIdx.x; e < Ee; e += stride) {
        uint2 p = packed[e];
        int c = (int)(p.x >> 16);
        int r = (int)(p.y >> 16);
        if (r >= lo && r < hi) adjR[atomicAdd(&nextR[r], 1)] = p.x;
        if (c >= lo && c < hi) adjC[atomicAdd(&nextC[c], 1)] = p.y;
    }
}

// ==== effective weights, layout [gate][k*128 + j], k=35 is the bias row ====
// f layout: [0..6]=X, [7..13]=Tx_o, [14..20]=Tx_i, [21..27]=T2_o, [28..34]=T2_i, [35]=1
__global__ __launch_bounds__(256) void weff_kernel(
    const float* __restrict__ Wz, const float* __restrict__ Wh,
    const float* __restrict__ bz, const float* __restrict__ bh,
    float* __restrict__ wzT, float* __restrict__ whT)
{
    int idx = blockIdx.x * 256 + threadIdx.x;
    if (idx >= 2 * 36 * 128) return;
    const float* W = (idx < 36 * 128) ? Wz : Wh;
    const float* B = (idx < 36 * 128) ? bz : bh;
    float* O       = (idx < 36 * 128) ? wzT : whT;
    int rem = idx % (36 * 128);
    int k = rem / 128, j = rem % 128;
    float v;
    if (k == 35) v = B[j];
    else {
        int p = k / 7, rr = k % 7;
        // W flat: ((d*3 + kk)*135 + rr)*128 + j
        if (p == 0)      v = W[(0 * 135 + rr) * 128 + j] + W[(3 * 135 + rr) * 128 + j];
        else if (p == 1) v = W[(1 * 135 + rr) * 128 + j];
        else if (p == 2) v = W[(4 * 135 + rr) * 128 + j];
        else if (p == 3) v = W[(2 * 135 + rr) * 128 + j];
        else             v = W[(5 * 135 + rr) * 128 + j];
    }
    O[k * 128 + j] = v;
}

// =================== init: Xh row (f16) and out column 0 ===================
__global__ __launch_bounds__(256) void init_kernel(
    const float* __restrict__ x, const float* __restrict__ env,
    const float* __restrict__ coords, __half* __restrict__ Xh,
    float* __restrict__ out)
{
    int i = blockIdx.x * 256 + threadIdx.x;
    if (i >= Nn) return;
    float xv = x[i * Tt];
    __half* r = Xh + (long)i * 8;
    r[0] = __float2half(xv);
    #pragma unroll
    for (int c = 0; c < 4; c++) r[1 + c] = __float2half(env[i * 48 + c * 12]);
    r[5] = __float2half(coords[i * 2 + 0]);
    r[6] = __float2half(coords[i * 2 + 1]);
    r[7] = __half(0.f);
    out[i * 13 + 0] = xv;
}

__device__ __forceinline__ void unpack8(const __half* p, float* v) {
    uint4 hv = *((const uint4*)p);
    float2 p0 = __half22float2(*(__half2*)&hv.x);
    float2 p1 = __half22float2(*(__half2*)&hv.y);
    float2 p2 = __half22float2(*(__half2*)&hv.z);
    float2 p3 = __half22float2(*(__half2*)&hv.w);
    v[0] = p0.x; v[1] = p0.y; v[2] = p1.x; v[3] = p1.y;
    v[4] = p2.x; v[5] = p2.y; v[6] = p3.x;
}

__device__ __forceinline__ void pack8(__half* p, const float* v) {
    __half2 q0 = __floats2half2_rn(v[0], v[1]);
    __half2 q1 = __floats2half2_rn(v[2], v[3]);
    __half2 q2 = __floats2half2_rn(v[4], v[5]);
    __half2 q3 = __floats2half2_rn(v[6], 0.f);
    uint4 st;
    st.x = *(unsigned*)&q0; st.y = *(unsigned*)&q1;
    st.z = *(unsigned*)&q2; st.w = *(unsigned*)&q3;
    *((uint4*)p) = st;
}

// ============== gather pass 1: Tx = inv * segsum(w * Xh[src]) ==============
// 8 threads per node: bit2 = dir (out/in), bits0-1 = sub.
__global__ __launch_bounds__(256) void gather1_kernel(
    const int* __restrict__ startR, const int* __restrict__ cntR,
    const unsigned* __restrict__ adjR,
    const int* __restrict__ startC, const int* __restrict__ cntC,
    const unsigned* __restrict__ adjC,
    const __half* __restrict__ Xh,
    __half* __restrict__ TxoH, __half* __restrict__ TxiH,
    float* __restrict__ inv_out, float* __restrict__ inv_in)
{
    int tid = blockIdx.x * 256 + threadIdx.x;
    if (tid >= Nn * 8) return;
    int node = tid >> 3;
    int dir = (tid >> 2) & 1, sub = tid & 3;
    const int*      st  = dir ? startC : startR;
    const int*      cn  = dir ? cntC : cntR;
    const unsigned* adj = dir ? adjC : adjR;
    int b = st[node], e = b + cn[node];
    float a[7] = {0.f, 0.f, 0.f, 0.f, 0.f, 0.f, 0.f};
    float sw = 0.f;
    for (int k = b + sub; k < e; k += 4) {
        unsigned ed = adj[k];
        float w = __half2float(__ushort_as_half((unsigned short)(ed & 0xffffu)));
        float xv[7];
        unpack8(Xh + (long)(ed >> 16) * 8, xv);
        #pragma unroll
        for (int q = 0; q < 7; q++) a[q] = fmaf(w, xv[q], a[q]);
        sw += w;
    }
    #pragma unroll
    for (int m = 1; m <= 2; m <<= 1) {
        #pragma unroll
        for (int q = 0; q < 7; q++) a[q] += __shfl_xor(a[q], m);
        sw += __shfl_xor(sw, m);
    }
    if (sub == 0) {
        float inv = sw > 0.f ? 1.f / sw : 0.f;
        (dir ? inv_in : inv_out)[node] = inv;
        #pragma unroll
        for (int q = 0; q < 7; q++) a[q] *= inv;
        pack8((dir ? TxiH : TxoH) + (long)node * 8, a);
    }
}

// ====== fused step2: second-order propagation (into LDS, fp32) + dense =====
// Block = 256 threads = 32 nodes.
// Phase A (g2): 8 threads/node (dir = bit2, sub = bits0-1); T2, Tx, X -> f_s.
// Phase B: channel-resident weights (72 VGPR/lane); wave w: channels
// (w&1)*64..+64 for node half (w>>1); pure register FMA inner loop.
__global__ __launch_bounds__(256) void step2_kernel(
    const int* __restrict__ startR, const int* __restrict__ cntR,
    const unsigned* __restrict__ adjR,
    const int* __restrict__ startC, const int* __restrict__ cntC,
    const unsigned* __restrict__ adjC,
    const float* __restrict__ inv_out, const float* __restrict__ inv_in,
    const float* __restrict__ env, const float* __restrict__ night,
    const float* __restrict__ wzT, const float* __restrict__ whT,
    const float* __restrict__ linW, const float* __restrict__ linb,
    __half* __restrict__ Xh,
    const __half* __restrict__ TxoH, const __half* __restrict__ TxiH,
    float* __restrict__ out, int t)
{
    __shared__ float f_s[32][36];
    __shared__ float part_s[2][32];
    int tid = threadIdx.x;
    int base = blockIdx.x * 32;

    // ---- phase A: T2 for this block's 32 nodes, straight into LDS ----
    {
        int nl = tid >> 3;
        int dir = (tid >> 2) & 1, sub = tid & 3;
        int node = base + nl;
        int nc = node < Nn ? node : Nn - 1;   // clamp; output stores guarded
        const int*      st  = dir ? startC : startR;
        const int*      cn  = dir ? cntC : cntR;
        const unsigned* adj = dir ? adjC : adjR;
        const __half*   src = dir ? TxiH : TxoH;
        int b = st[nc], e = b + cn[nc];
        float a[7] = {0.f, 0.f, 0.f, 0.f, 0.f, 0.f, 0.f};
        for (int k = b + sub; k < e; k += 4) {
            unsigned ed = adj[k];
            float w = __half2float(__ushort_as_half((unsigned short)(ed & 0xffffu)));
            float xv[7];
            unpack8(src + (long)(ed >> 16) * 8, xv);
            #pragma unroll
            for (int q = 0; q < 7; q++) a[q] = fmaf(w, xv[q], a[q]);
        }
        #pragma unroll
        for (int m = 1; m <= 2; m <<= 1) {
            #pragma unroll
            for (int q = 0; q < 7; q++) a[q] += __shfl_xor(a[q], m);
        }
        if (sub == 0) {
            float s2 = 2.f * (dir ? inv_in[nc] : inv_out[nc]);
            float xv[7], tx[7];
            unpack8(Xh + (long)nc * 8, xv);
            unpack8(src + (long)nc * 8, tx);     // own Tx row (dir-matched)
            #pragma unroll
            for (int q = 0; q < 7; q++) {
                f_s[nl][21 + 7 * dir + q] = fmaf(s2, a[q], -xv[q]);
                f_s[nl][7 + 7 * dir + q]  = tx[q];
            }
            if (dir == 0) {
                #pragma unroll
                for (int q = 0; q < 7; q++) f_s[nl][q] = xv[q];
                f_s[nl][35] = 1.f;
            }
        }
    }
    __syncthreads();

    // ---- phase B: dense 36x128x2 contraction + activations + output ----
    int lane = tid & 63;
    int wave = tid >> 6;
    int chSel = wave & 1;
    int ch = chSel * 64 + lane;
    int half_id = wave >> 1;
    float wz[36], wh[36];
    #pragma unroll
    for (int k = 0; k < 36; k++) wz[k] = wzT[k * 128 + ch];
    #pragma unroll
    for (int k = 0; k < 36; k++) wh[k] = whT[k * 128 + ch];
    float lw = linW[ch];
    float lb = linb[0];

    #pragma unroll 1
    for (int n = 0; n < 16; n++) {
        int ni = half_id * 16 + n;
        const float4* fv = (const float4*)f_s[ni];   // broadcast reads
        float hz = 0.f, hh = 0.f;
        #pragma unroll
        for (int q = 0; q < 9; q++) {
            float4 fq = fv[q];
            hz = fmaf(fq.x, wz[q*4+0], hz); hh = fmaf(fq.x, wh[q*4+0], hh);
            hz = fmaf(fq.y, wz[q*4+1], hz); hh = fmaf(fq.y, wh[q*4+1], hh);
            hz = fmaf(fq.z, wz[q*4+2], hz); hh = fmaf(fq.z, wh[q*4+2], hh);
            hz = fmaf(fq.w, wz[q*4+3], hz); hh = fmaf(fq.w, wh[q*4+3], hh);
        }
        float z  = 1.f / (1.f + __expf(-hz));
        float e2 = __expf(2.f * hh);
        float ht = 1.f - 2.f / (e2 + 1.f);           // tanh
        float v = fmaxf((1.f - z) * ht, 0.f) * lw;   // (1-Z)*H~, relu, lin
        v += __shfl_xor(v, 1);  v += __shfl_xor(v, 2);  v += __shfl_xor(v, 4);
        v += __shfl_xor(v, 8);  v += __shfl_xor(v, 16); v += __shfl_xor(v, 32);
        if (lane == 0) part_s[chSel][ni] = v;
    }
    __syncthreads();
    if (tid < 32) {
        int node = base + tid;
        if (node < Nn) {
            float o = part_s[0][tid] + part_s[1][tid] + lb;
            o *= night[(long)node * 13 + t + 1];
            out[(long)node * 13 + t + 1] = o;
            if (t + 1 < Tt) {
                __half* xr = Xh + (long)node * 8;
                xr[0] = __float2half(o);
                #pragma unroll
                for (int c = 0; c < 4; c++)
                    xr[1 + c] = __float2half(env[(long)node * 48 + c * 12 + t + 1]);
            }
        }
    }
}

extern "C" void kernel_launch(void* const* d_in, const int* in_sizes, int n_in,
                              void* d_out, int out_size, void* d_ws, size_t ws_size,
                              hipStream_t stream) {
    const float* x      = (const float*)d_in[0];
    const float* env    = (const float*)d_in[1];
    const float* coords = (const float*)d_in[2];
    const int*   ei     = (const int*)d_in[3];
    const float* ew     = (const float*)d_in[4];
    const float* night  = (const float*)d_in[5];
    const float* Wz     = (const float*)d_in[6];
    const float* bz     = (const float*)d_in[7];
    // d_in[8]=Wr, d_in[9]=br unused (R gate never affects output)
    const float* Wh     = (const float*)d_in[10];
    const float* bh     = (const float*)d_in[11];
    const float* linW   = (const float*)d_in[12];
    const float* linb   = (const float*)d_in[13];
    float* out = (float*)d_out;

    float* w = (float*)d_ws;
    float* wzT     = w;                     // 36*128
    float* whT     = w + 4608;
    float* inv_out = w + 9216;              // N
    float* inv_in  = w + 59216;
    __half* Xh   = (__half*)(w + 109216);   // N x 8 halves (16B-aligned offsets)
    __half* TxoH = (__half*)(w + 309216);
    __half* TxiH = (__half*)(w + 509216);
    int* cntR    = (int*)(w + 709216);      // N
    int* cntC    = cntR + 50000;
    int* startR  = cntC + 50000;            // N
    int* startC  = startR + 50000;
    int* nextR   = startC + 50000;          // N
    int* nextC   = nextR + 50000;
    int* bsum    = nextC + 50000;           // 2 x 256
    int* bbase   = bsum + 512;              // 2 x 256
    uint2* packed  = (uint2*)(bbase + 512); // E x 8B (offset even -> 8B aligned)
    unsigned* adjR = (unsigned*)(packed + Ee);   // E x 4B
    unsigned* adjC = adjR + Ee;

    // ---- CSR build (per launch; ws is re-poisoned every call) ----
    hipMemsetAsync(cntR, 0, 2 * Nn * sizeof(int), stream);
    pack_hist_kernel<<<(Ee + 255) / 256, 256, 0, stream>>>(ei, ew, packed, cntR, cntC);
    scanA_kernel<<<dim3(SCB, 2), 256, 0, stream>>>(cntR, cntC, bsum);
    scanB_kernel<<<2, 256, 0, stream>>>(bsum, bbase);
    scanC_kernel<<<dim3(SCB, 2), 256, 0, stream>>>(
        cntR, cntC, bbase, startR, startC, nextR, nextC);
    scatter_banded<<<8 * 256, 256, 0, stream>>>(packed, nextR, nextC, adjR, adjC);

    weff_kernel<<<(2 * 36 * 128 + 255) / 256, 256, 0, stream>>>(Wz, Wh, bz, bh, wzT, whT);
    init_kernel<<<(Nn + 255) / 256, 256, 0, stream>>>(x, env, coords, Xh, out);

    for (int t = 0; t < Tt; t++) {
        gather1_kernel<<<(Nn * 8 + 255) / 256, 256, 0, stream>>>(
            startR, cntR, adjR, startC, cntC, adjC, Xh, TxoH, TxiH, inv_out, inv_in);
        step2_kernel<<<(Nn + 31) / 32, 256, 0, stream>>>(
            startR, cntR, adjR, startC, cntC, adjC, inv_out, inv_in,
            env, night, wzT, whT, linW, linb, Xh, TxoH, TxiH, out, t);
    }
}

// Round 7
// 788.248 us; speedup vs baseline: 19.6495x; 1.0344x over previous
//
#include <hip/hip_runtime.h>
#include <hip/hip_fp16.h>

#define Nn 50000
#define Ee 800000
#define Tt 12
#define NBAND 8
#define BAND 6250        // Nn / NBAND exactly
#define SCB 196          // scan blocks per half: 196*256 >= Nn
// HID=128, K=3, F_IN=7, effective features = 35 (+1 bias slot)
// Node feature rows: 8 x f16 = 16 B (one dwordx4 gather).
// Packed edge record (8 B): {lo = (c<<16)|wb, hi = (r<<16)|wb}, wb = f16(w).
// adjR entry = lo (keyed by r), adjC entry = hi (keyed by c).

// ============ pack edges + degree histogram (one pass over edges) ==========
__global__ __launch_bounds__(256) void pack_hist_kernel(
    const int* __restrict__ ei, const float* __restrict__ ew,
    uint2* __restrict__ packed, int* __restrict__ cntR, int* __restrict__ cntC)
{
    int e = blockIdx.x * 256 + threadIdx.x;
    if (e >= Ee) return;
    int r = ei[e], c = ei[Ee + e];
    unsigned wb = __half_as_ushort(__float2half(ew[e]));
    packed[e] = make_uint2(((unsigned)c << 16) | wb, ((unsigned)r << 16) | wb);
    atomicAdd(&cntR[r], 1);
    atomicAdd(&cntC[c], 1);
}

// ---- 3-phase multi-block exclusive scan of cntR / cntC --------------------
__global__ __launch_bounds__(256) void scanA_kernel(
    const int* __restrict__ cntR, const int* __restrict__ cntC,
    int* __restrict__ bsum)
{
    const int* cnt = blockIdx.y ? cntC : cntR;
    int i = blockIdx.x * 256 + threadIdx.x;
    int v = (i < Nn) ? cnt[i] : 0;
    __shared__ int ws_[4];
    v += __shfl_xor(v, 1);  v += __shfl_xor(v, 2);  v += __shfl_xor(v, 4);
    v += __shfl_xor(v, 8);  v += __shfl_xor(v, 16); v += __shfl_xor(v, 32);
    if ((threadIdx.x & 63) == 0) ws_[threadIdx.x >> 6] = v;
    __syncthreads();
    if (threadIdx.x == 0)
        bsum[blockIdx.y * 256 + blockIdx.x] = ws_[0] + ws_[1] + ws_[2] + ws_[3];
}

__global__ __launch_bounds__(256) void scanB_kernel(
    const int* __restrict__ bsum, int* __restrict__ bbase)
{
    int y = blockIdx.x;
    __shared__ int s[256];
    int t = threadIdx.x;
    int v = (t < SCB) ? bsum[y * 256 + t] : 0;
    s[t] = v;
    __syncthreads();
    for (int off = 1; off < 256; off <<= 1) {
        int u = (t >= off) ? s[t - off] : 0;
        __syncthreads();
        s[t] += u;
        __syncthreads();
    }
    bbase[y * 256 + t] = s[t] - v;   // exclusive
}

__global__ __launch_bounds__(256) void scanC_kernel(
    const int* __restrict__ cntR, const int* __restrict__ cntC,
    const int* __restrict__ bbase,
    int* __restrict__ startR, int* __restrict__ startC,
    int* __restrict__ nextR, int* __restrict__ nextC)
{
    int y = blockIdx.y;
    const int* cnt = y ? cntC : cntR;
    int* start     = y ? startC : startR;
    int* nxt       = y ? nextC : nextR;
    int i = blockIdx.x * 256 + threadIdx.x;
    int v = (i < Nn) ? cnt[i] : 0;
    __shared__ int s[256];
    int t = threadIdx.x;
    s[t] = v;
    __syncthreads();
    for (int off = 1; off < 256; off <<= 1) {
        int u = (t >= off) ? s[t - off] : 0;
        __syncthreads();
        s[t] += u;
        __syncthreads();
    }
    int st = bbase[y * 256 + blockIdx.x] + s[t] - v;
    if (i < Nn) { start[i] = st; nxt[i] = st; }
}

// Banded scatter: block handles destination band (blockIdx & 7); with the
// blockIdx%8 -> XCD round-robin each band's write region stays L2-hot so
// lines fill before writeback.
__global__ __launch_bounds__(256) void scatter_banded(
    const uint2* __restrict__ packed,
    int* __restrict__ nextR, int* __restrict__ nextC,
    unsigned* __restrict__ adjR, unsigned* __restrict__ adjC)
{
    int band = blockIdx.x & (NBAND - 1);
    int chunk = blockIdx.x >> 3;
    int lo = band * BAND, hi = lo + BAND;
    int stride = (gridDim.x >> 3) * 256;
    for (int e = chunk * 256 + threadIdx.x; e < Ee; e += stride) {
        uint2 p = packed[e];
        int c = (int)(p.x >> 16);
        int r = (int)(p.y >> 16);
        if (r >= lo && r < hi) adjR[atomicAdd(&nextR[r], 1)] = p.x;
        if (c >= lo && c < hi) adjC[atomicAdd(&nextC[c], 1)] = p.y;
    }
}

// ==== effective weights, layout [gate][k*128 + j], k=35 is the bias row ====
// f layout: [0..6]=X, [7..13]=Tx_o, [14..20]=Tx_i, [21..27]=T2_o, [28..34]=T2_i, [35]=1
__global__ __launch_bounds__(256) void weff_kernel(
    const float* __restrict__ Wz, const float* __restrict__ Wh,
    const float* __restrict__ bz, const float* __restrict__ bh,
    float* __restrict__ wzT, float* __restrict__ whT)
{
    int idx = blockIdx.x * 256 + threadIdx.x;
    if (idx >= 2 * 36 * 128) return;
    const float* W = (idx < 36 * 128) ? Wz : Wh;
    const float* B = (idx < 36 * 128) ? bz : bh;
    float* O       = (idx < 36 * 128) ? wzT : whT;
    int rem = idx % (36 * 128);
    int k = rem / 128, j = rem % 128;
    float v;
    if (k == 35) v = B[j];
    else {
        int p = k / 7, rr = k % 7;
        // W flat: ((d*3 + kk)*135 + rr)*128 + j
        if (p == 0)      v = W[(0 * 135 + rr) * 128 + j] + W[(3 * 135 + rr) * 128 + j];
        else if (p == 1) v = W[(1 * 135 + rr) * 128 + j];
        else if (p == 2) v = W[(4 * 135 + rr) * 128 + j];
        else if (p == 3) v = W[(2 * 135 + rr) * 128 + j];
        else             v = W[(5 * 135 + rr) * 128 + j];
    }
    O[k * 128 + j] = v;
}

// =================== init: Xh row (f16) and out column 0 ===================
__global__ __launch_bounds__(256) void init_kernel(
    const float* __restrict__ x, const float* __restrict__ env,
    const float* __restrict__ coords, __half* __restrict__ Xh,
    float* __restrict__ out)
{
    int i = blockIdx.x * 256 + threadIdx.x;
    if (i >= Nn) return;
    float xv = x[i * Tt];
    __half* r = Xh + (long)i * 8;
    r[0] = __float2half(xv);
    #pragma unroll
    for (int c = 0; c < 4; c++) r[1 + c] = __float2half(env[i * 48 + c * 12]);
    r[5] = __float2half(coords[i * 2 + 0]);
    r[6] = __float2half(coords[i * 2 + 1]);
    r[7] = __half(0.f);
    out[i * 13 + 0] = xv;
}

__device__ __forceinline__ void unpack8(const __half* p, float* v) {
    uint4 hv = *((const uint4*)p);
    float2 p0 = __half22float2(*(__half2*)&hv.x);
    float2 p1 = __half22float2(*(__half2*)&hv.y);
    float2 p2 = __half22float2(*(__half2*)&hv.z);
    float2 p3 = __half22float2(*(__half2*)&hv.w);
    v[0] = p0.x; v[1] = p0.y; v[2] = p1.x; v[3] = p1.y;
    v[4] = p2.x; v[5] = p2.y; v[6] = p3.x;
}

__device__ __forceinline__ void pack8(__half* p, const float* v) {
    __half2 q0 = __floats2half2_rn(v[0], v[1]);
    __half2 q1 = __floats2half2_rn(v[2], v[3]);
    __half2 q2 = __floats2half2_rn(v[4], v[5]);
    __half2 q3 = __floats2half2_rn(v[6], 0.f);
    uint4 st;
    st.x = *(unsigned*)&q0; st.y = *(unsigned*)&q1;
    st.z = *(unsigned*)&q2; st.w = *(unsigned*)&q3;
    *((uint4*)p) = st;
}

// accumulate a[0..6] += w * halfrow(hv)
__device__ __forceinline__ void acc7(float* a, float w, uint4 hv) {
    float2 p0 = __half22float2(*(__half2*)&hv.x);
    float2 p1 = __half22float2(*(__half2*)&hv.y);
    float2 p2 = __half22float2(*(__half2*)&hv.z);
    float2 p3 = __half22float2(*(__half2*)&hv.w);
    a[0] = fmaf(w, p0.x, a[0]); a[1] = fmaf(w, p0.y, a[1]);
    a[2] = fmaf(w, p1.x, a[2]); a[3] = fmaf(w, p1.y, a[3]);
    a[4] = fmaf(w, p2.x, a[4]); a[5] = fmaf(w, p2.y, a[5]);
    a[6] = fmaf(w, p3.x, a[6]);
}

__device__ __forceinline__ float wdec(unsigned ed) {
    return __half2float(__ushort_as_half((unsigned short)(ed & 0xffffu)));
}

// ============== gather pass 1: Tx = inv * segsum(w * Xh[src]) ==============
// 8 threads per node: bit2 = dir (out/in), bits0-1 = sub. Inner loop batches
// 4 strided adj entries -> 4 independent 16B gathers in flight (MLP x4).
__global__ __launch_bounds__(256) void gather1_kernel(
    const int* __restrict__ startR, const int* __restrict__ cntR,
    const unsigned* __restrict__ adjR,
    const int* __restrict__ startC, const int* __restrict__ cntC,
    const unsigned* __restrict__ adjC,
    const __half* __restrict__ Xh,
    __half* __restrict__ TxoH, __half* __restrict__ TxiH,
    float* __restrict__ inv_out, float* __restrict__ inv_in)
{
    int tid = blockIdx.x * 256 + threadIdx.x;
    if (tid >= Nn * 8) return;
    int node = tid >> 3;
    int dir = (tid >> 2) & 1, sub = tid & 3;
    const int*      st  = dir ? startC : startR;
    const int*      cn  = dir ? cntC : cntR;
    const unsigned* adj = dir ? adjC : adjR;
    int b = st[node], e = b + cn[node];
    float a[7] = {0.f, 0.f, 0.f, 0.f, 0.f, 0.f, 0.f};
    float sw = 0.f;
    int k = b + sub;
    for (; k + 12 < e; k += 16) {
        unsigned e0 = adj[k], e1 = adj[k + 4], e2 = adj[k + 8], e3 = adj[k + 12];
        uint4 r0 = *(const uint4*)(Xh + (long)(e0 >> 16) * 8);
        uint4 r1 = *(const uint4*)(Xh + (long)(e1 >> 16) * 8);
        uint4 r2 = *(const uint4*)(Xh + (long)(e2 >> 16) * 8);
        uint4 r3 = *(const uint4*)(Xh + (long)(e3 >> 16) * 8);
        float w0 = wdec(e0), w1 = wdec(e1), w2 = wdec(e2), w3 = wdec(e3);
        acc7(a, w0, r0); acc7(a, w1, r1); acc7(a, w2, r2); acc7(a, w3, r3);
        sw += (w0 + w1) + (w2 + w3);
    }
    for (; k < e; k += 4) {
        unsigned ed = adj[k];
        uint4 rv = *(const uint4*)(Xh + (long)(ed >> 16) * 8);
        float w = wdec(ed);
        acc7(a, w, rv);
        sw += w;
    }
    #pragma unroll
    for (int m = 1; m <= 2; m <<= 1) {
        #pragma unroll
        for (int q = 0; q < 7; q++) a[q] += __shfl_xor(a[q], m);
        sw += __shfl_xor(sw, m);
    }
    if (sub == 0) {
        float inv = sw > 0.f ? 1.f / sw : 0.f;
        (dir ? inv_in : inv_out)[node] = inv;
        #pragma unroll
        for (int q = 0; q < 7; q++) a[q] *= inv;
        pack8((dir ? TxiH : TxoH) + (long)node * 8, a);
    }
}

// ====== fused step2: second-order propagation (into LDS, fp32) + dense =====
// Block = 256 threads = 32 nodes.
// Phase A (g2): 8 threads/node (dir = bit2, sub = bits0-1); T2, Tx, X -> f_s.
// Phase B: channel-resident weights (72 VGPR/lane); wave w: channels
// (w&1)*64..+64 for node half (w>>1); pure register FMA inner loop.
__global__ __launch_bounds__(256) void step2_kernel(
    const int* __restrict__ startR, const int* __restrict__ cntR,
    const unsigned* __restrict__ adjR,
    const int* __restrict__ startC, const int* __restrict__ cntC,
    const unsigned* __restrict__ adjC,
    const float* __restrict__ inv_out, const float* __restrict__ inv_in,
    const float* __restrict__ env, const float* __restrict__ night,
    const float* __restrict__ wzT, const float* __restrict__ whT,
    const float* __restrict__ linW, const float* __restrict__ linb,
    __half* __restrict__ Xh,
    const __half* __restrict__ TxoH, const __half* __restrict__ TxiH,
    float* __restrict__ out, int t)
{
    __shared__ float f_s[32][36];
    __shared__ float part_s[2][32];
    int tid = threadIdx.x;
    int base = blockIdx.x * 32;

    // ---- phase A: T2 for this block's 32 nodes, straight into LDS ----
    {
        int nl = tid >> 3;
        int dir = (tid >> 2) & 1, sub = tid & 3;
        int node = base + nl;
        int nc = node < Nn ? node : Nn - 1;   // clamp; output stores guarded
        const int*      st  = dir ? startC : startR;
        const int*      cn  = dir ? cntC : cntR;
        const unsigned* adj = dir ? adjC : adjR;
        const __half*   src = dir ? TxiH : TxoH;
        int b = st[nc], e = b + cn[nc];
        float a[7] = {0.f, 0.f, 0.f, 0.f, 0.f, 0.f, 0.f};
        int k = b + sub;
        for (; k + 12 < e; k += 16) {
            unsigned e0 = adj[k], e1 = adj[k + 4], e2 = adj[k + 8], e3 = adj[k + 12];
            uint4 r0 = *(const uint4*)(src + (long)(e0 >> 16) * 8);
            uint4 r1 = *(const uint4*)(src + (long)(e1 >> 16) * 8);
            uint4 r2 = *(const uint4*)(src + (long)(e2 >> 16) * 8);
            uint4 r3 = *(const uint4*)(src + (long)(e3 >> 16) * 8);
            float w0 = wdec(e0), w1 = wdec(e1), w2 = wdec(e2), w3 = wdec(e3);
            acc7(a, w0, r0); acc7(a, w1, r1); acc7(a, w2, r2); acc7(a, w3, r3);
        }
        for (; k < e; k += 4) {
            unsigned ed = adj[k];
            uint4 rv = *(const uint4*)(src + (long)(ed >> 16) * 8);
            acc7(a, wdec(ed), rv);
        }
        #pragma unroll
        for (int m = 1; m <= 2; m <<= 1) {
            #pragma unroll
            for (int q = 0; q < 7; q++) a[q] += __shfl_xor(a[q], m);
        }
        if (sub == 0) {
            float s2 = 2.f * (dir ? inv_in[nc] : inv_out[nc]);
            float xv[7], tx[7];
            unpack8(Xh + (long)nc * 8, xv);
            unpack8(src + (long)nc * 8, tx);     // own Tx row (dir-matched)
            #pragma unroll
            for (int q = 0; q < 7; q++) {
                f_s[nl][21 + 7 * dir + q] = fmaf(s2, a[q], -xv[q]);
                f_s[nl][7 + 7 * dir + q]  = tx[q];
            }
            if (dir == 0) {
                #pragma unroll
                for (int q = 0; q < 7; q++) f_s[nl][q] = xv[q];
                f_s[nl][35] = 1.f;
            }
        }
    }
    __syncthreads();

    // ---- phase B: dense 36x128x2 contraction + activations + output ----
    int lane = tid & 63;
    int wave = tid >> 6;
    int chSel = wave & 1;
    int ch = chSel * 64 + lane;
    int half_id = wave >> 1;
    float wz[36], wh[36];
    #pragma unroll
    for (int k = 0; k < 36; k++) wz[k] = wzT[k * 128 + ch];
    #pragma unroll
    for (int k = 0; k < 36; k++) wh[k] = whT[k * 128 + ch];
    float lw = linW[ch];
    float lb = linb[0];

    #pragma unroll 1
    for (int n = 0; n < 16; n++) {
        int ni = half_id * 16 + n;
        const float4* fv = (const float4*)f_s[ni];   // broadcast reads
        float hz = 0.f, hh = 0.f;
        #pragma unroll
        for (int q = 0; q < 9; q++) {
            float4 fq = fv[q];
            hz = fmaf(fq.x, wz[q*4+0], hz); hh = fmaf(fq.x, wh[q*4+0], hh);
            hz = fmaf(fq.y, wz[q*4+1], hz); hh = fmaf(fq.y, wh[q*4+1], hh);
            hz = fmaf(fq.z, wz[q*4+2], hz); hh = fmaf(fq.z, wh[q*4+2], hh);
            hz = fmaf(fq.w, wz[q*4+3], hz); hh = fmaf(fq.w, wh[q*4+3], hh);
        }
        float z  = 1.f / (1.f + __expf(-hz));
        float e2 = __expf(2.f * hh);
        float ht = 1.f - 2.f / (e2 + 1.f);           // tanh
        float v = fmaxf((1.f - z) * ht, 0.f) * lw;   // (1-Z)*H~, relu, lin
        v += __shfl_xor(v, 1);  v += __shfl_xor(v, 2);  v += __shfl_xor(v, 4);
        v += __shfl_xor(v, 8);  v += __shfl_xor(v, 16); v += __shfl_xor(v, 32);
        if (lane == 0) part_s[chSel][ni] = v;
    }
    __syncthreads();
    if (tid < 32) {
        int node = base + tid;
        if (node < Nn) {
            float o = part_s[0][tid] + part_s[1][tid] + lb;
            o *= night[(long)node * 13 + t + 1];
            out[(long)node * 13 + t + 1] = o;
            if (t + 1 < Tt) {
                __half* xr = Xh + (long)node * 8;
                xr[0] = __float2half(o);
                #pragma unroll
                for (int c = 0; c < 4; c++)
                    xr[1 + c] = __float2half(env[(long)node * 48 + c * 12 + t + 1]);
            }
        }
    }
}

extern "C" void kernel_launch(void* const* d_in, const int* in_sizes, int n_in,
                              void* d_out, int out_size, void* d_ws, size_t ws_size,
                              hipStream_t stream) {
    const float* x      = (const float*)d_in[0];
    const float* env    = (const float*)d_in[1];
    const float* coords = (const float*)d_in[2];
    const int*   ei     = (const int*)d_in[3];
    const float* ew     = (const float*)d_in[4];
    const float* night  = (const float*)d_in[5];
    const float* Wz     = (const float*)d_in[6];
    const float* bz     = (const float*)d_in[7];
    // d_in[8]=Wr, d_in[9]=br unused (R gate never affects output)
    const float* Wh     = (const float*)d_in[10];
    const float* bh     = (const float*)d_in[11];
    const float* linW   = (const float*)d_in[12];
    const float* linb   = (const float*)d_in[13];
    float* out = (float*)d_out;

    float* w = (float*)d_ws;
    float* wzT     = w;                     // 36*128
    float* whT     = w + 4608;
    float* inv_out = w + 9216;              // N
    float* inv_in  = w + 59216;
    __half* Xh   = (__half*)(w + 109216);   // N x 8 halves (16B-aligned offsets)
    __half* TxoH = (__half*)(w + 309216);
    __half* TxiH = (__half*)(w + 509216);
    int* cntR    = (int*)(w + 709216);      // N
    int* cntC    = cntR + 50000;
    int* startR  = cntC + 50000;            // N
    int* startC  = startR + 50000;
    int* nextR   = startC + 50000;          // N
    int* nextC   = nextR + 50000;
    int* bsum    = nextC + 50000;           // 2 x 256
    int* bbase   = bsum + 512;              // 2 x 256
    uint2* packed  = (uint2*)(bbase + 512); // E x 8B (offset even -> 8B aligned)
    unsigned* adjR = (unsigned*)(packed + Ee);   // E x 4B
    unsigned* adjC = adjR + Ee;

    // ---- CSR build (per launch; ws is re-poisoned every call) ----
    hipMemsetAsync(cntR, 0, 2 * Nn * sizeof(int), stream);
    pack_hist_kernel<<<(Ee + 255) / 256, 256, 0, stream>>>(ei, ew, packed, cntR, cntC);
    scanA_kernel<<<dim3(SCB, 2), 256, 0, stream>>>(cntR, cntC, bsum);
    scanB_kernel<<<2, 256, 0, stream>>>(bsum, bbase);
    scanC_kernel<<<dim3(SCB, 2), 256, 0, stream>>>(
        cntR, cntC, bbase, startR, startC, nextR, nextC);
    scatter_banded<<<8 * 256, 256, 0, stream>>>(packed, nextR, nextC, adjR, adjC);

    weff_kernel<<<(2 * 36 * 128 + 255) / 256, 256, 0, stream>>>(Wz, Wh, bz, bh, wzT, whT);
    init_kernel<<<(Nn + 255) / 256, 256, 0, stream>>>(x, env, coords, Xh, out);

    for (int t = 0; t < Tt; t++) {
        gather1_kernel<<<(Nn * 8 + 255) / 256, 256, 0, stream>>>(
            startR, cntR, adjR, startC, cntC, adjC, Xh, TxoH, TxiH, inv_out, inv_in);
        step2_kernel<<<(Nn + 31) / 32, 256, 0, stream>>>(
            startR, cntR, adjR, startC, cntC, adjC, inv_out, inv_in,
            env, night, wzT, whT, linW, linb, Xh, TxoH, TxiH, out, t);
    }
}